// Round 7
// baseline (1757.379 us; speedup 1.0000x reference)
//
#include <hip/hip_runtime.h>
#include <hip/hip_cooperative_groups.h>
#include <math.h>

namespace cg = cooperative_groups;

typedef unsigned short ushort_t;
typedef unsigned int uint_t;

__device__ __forceinline__ float bf2f(ushort_t u) {
    union { uint_t i; float f; } x; x.i = ((uint_t)u) << 16; return x.f;
}
__device__ __forceinline__ ushort_t f2bf(float f) {
    union { float f; uint_t i; } x; x.f = f;
    uint_t r = x.i + 0x7FFFu + ((x.i >> 16) & 1u);
    return (ushort_t)(r >> 16);
}

struct GArgs {
    const float* x; const int* srcv; const int* dstv;
    const float* W0; const float* W1; const float* W2; const float* W3; const float* W4;
    const float* b0; const float* b1; const float* b2; const float* b3; const float* b4;
    const float* g0; const float* g1; const float* g2; const float* g3;
    const float* e0; const float* e1; const float* e2; const float* e3;
    float* out;
    int* cnt; int* row_start; int* cursor; int* csr_src;
    float* dinv; float* stats; float* wbias;
    ushort_t* xb; ushort_t* Wt; ushort_t* h2; ushort_t* tmpb;
    int N, E;
};

__device__ __forceinline__ int dimOf(int i) {
    switch (i) { case 0: return 256; case 1: return 220; case 2: return 150;
                 case 3: return 100; case 4: return 60; default: return 17; }
}
__device__ __forceinline__ const float* selW(const GArgs& a, int l) {
    switch (l) { case 0: return a.W0; case 1: return a.W1; case 2: return a.W2;
                 case 3: return a.W3; default: return a.W4; }
}
__device__ __forceinline__ const float* selB(const GArgs& a, int l) {
    switch (l) { case 0: return a.b0; case 1: return a.b1; case 2: return a.b2;
                 case 3: return a.b3; default: return a.b4; }
}
__device__ __forceinline__ const float* selG(const GArgs& a, int l) {
    switch (l) { case 0: return a.g0; case 1: return a.g1; case 2: return a.g2;
                 default: return a.g3; }
}
__device__ __forceinline__ const float* selE(const GArgs& a, int l) {
    switch (l) { case 0: return a.e0; case 1: return a.e1; case 2: return a.e2;
                 default: return a.e3; }
}

__global__ __launch_bounds__(256, 4) void k_mega(GArgs a) {
    cg::grid_group grid = cg::this_grid();
    const int tid = threadIdx.x;
    const int bid = blockIdx.x;
    const int nb  = gridDim.x;
    const int gthreads = nb * 256;
    const int gt = bid * 256 + tid;

    __shared__ float smf[512];
    __shared__ int   smi[256];

    typedef __attribute__((ext_vector_type(8))) short short8;
    typedef __attribute__((ext_vector_type(4))) float floatx4;

    // ---- phase A: zero cnt + stats; convert x -> bf16 ----
    for (int i = gt; i < a.N; i += gthreads) a.cnt[i] = 0;
    for (int i = gt; i < 5 * 512; i += gthreads) a.stats[i] = 0.f;
    {
        const int n4 = a.N * 64;
        for (int i = gt; i < n4; i += gthreads) {
            float4 v = ((const float4*)a.x)[i];
            ushort_t* o = a.xb + i * 4;
            o[0] = f2bf(v.x); o[1] = f2bf(v.y); o[2] = f2bf(v.z); o[3] = f2bf(v.w);
        }
    }
    grid.sync();

    // ---- phase B: degree histogram ----
    for (int e = gt; e < a.E; e += gthreads) atomicAdd(&a.cnt[a.dstv[e]], 1);
    grid.sync();

    // ---- phase C: scan (block 0) -> row_start, cursor, dinv ----
    if (bid == 0) {
        const int chunk = (a.N + 255) >> 8;
        const int lo = tid * chunk;
        const int hi = min(lo + chunk, a.N);
        int s = 0;
        for (int i = lo; i < hi; ++i) s += a.cnt[i];
        smi[tid] = s;
        __syncthreads();
        for (int off = 1; off < 256; off <<= 1) {
            int v = (tid >= off) ? smi[tid - off] : 0;
            __syncthreads();
            smi[tid] += v;
            __syncthreads();
        }
        int run = smi[tid] - s;
        for (int i = lo; i < hi; ++i) {
            int c = a.cnt[i];
            a.row_start[i] = run;
            a.cursor[i] = run;
            a.dinv[i] = rsqrtf(1.0f + (float)c);
            run += c;
        }
        if (tid == 255) a.row_start[a.N] = smi[255];
    }
    grid.sync();

    // ---- phase D: CSR fill + prep layer 0 (identity affine) ----
    for (int e = gt; e < a.E; e += gthreads) {
        int pos = atomicAdd(&a.cursor[a.dstv[e]], 1);
        a.csr_src[pos] = a.srcv[e];
    }
    // prep(0) inline below via the common path (l=0 -> sc=1, sh=0)
    {
        const int l = 0;
        const int K = dimOf(l), M = dimOf(l + 1);
        const int Kp = (K + 31) & ~31, Mp = (M + 15) & ~15;
        if (tid < K) { smf[tid] = 1.f; smf[256 + tid] = 0.f; }
        __syncthreads();
        const float* W = selW(a, l);
        const long tot = (long)Mp * Kp;
        for (long idx = gt; idx < tot; idx += gthreads) {
            int j = (int)(idx / Kp);
            int k = (int)(idx - (long)j * Kp);
            float v = 0.f;
            if (k < K && j < M) v = smf[k] * W[(long)k * M + j];
            a.Wt[idx] = f2bf(v);
        }
        for (int u = gt; u < 4 * Mp; u += gthreads) {
            int j = u >> 2;
            float s = 0.f;   // layer 0: shift = 0 -> wbias = 0
            s += __shfl_xor(s, 1, 64);
            s += __shfl_xor(s, 2, 64);
            if ((u & 3) == 0) a.wbias[j] = s;
        }
    }
    grid.sync();

    // ---- layer loop ----
    for (int l = 0; l < 5; ++l) {
        // ---- GEMM phase: h2 = rowscale(dinv) * (X @ Wt^T + wbias) ----
        {
            const int K = dimOf(l), M = dimOf(l + 1);
            const int Kp = (K + 31) & ~31, Mp = (M + 15) & ~15;
            const ushort_t* X = (l == 0) ? a.xb : a.tmpb;
            const int ni = (a.N + 15) >> 4;
            const int nj = (Mp + 63) >> 6;
            const int wid = (bid << 2) + (tid >> 6);
            const int nw = nb << 2;
            const int lane = tid & 63, m = lane & 15, quad = lane >> 4;
            for (int t = wid; t < ni * nj; t += nw) {
                int bi = t / nj, bj = t - bi * nj;
                int i0 = bi << 4, j0 = bj << 6;
                int ntiles = (Mp - j0) >> 4; if (ntiles > 4) ntiles = 4;
                floatx4 acc[4];
                #pragma unroll
                for (int q = 0; q < 4; ++q) { acc[q].x = 0.f; acc[q].y = 0.f; acc[q].z = 0.f; acc[q].w = 0.f; }
                int ra = i0 + m; if (ra > a.N - 1) ra = a.N - 1;
                const ushort_t* arow = X + (long)ra * Kp + quad * 8;
                const ushort_t* brow = a.Wt + (long)(j0 + m) * Kp + quad * 8;
                for (int k0 = 0; k0 < Kp; k0 += 32) {
                    short8 av = *(const short8*)(arow + k0);
                    #pragma unroll
                    for (int q = 0; q < 4; ++q) {
                        if (q < ntiles) {
                            short8 bv = *(const short8*)(brow + (long)q * 16 * Kp + k0);
                            acc[q] = __builtin_amdgcn_mfma_f32_16x16x32_bf16(av, bv, acc[q], 0, 0, 0);
                        }
                    }
                }
                #pragma unroll
                for (int q = 0; q < 4; ++q) {
                    if (q < ntiles) {
                        int j = j0 + q * 16 + m;
                        float wb = a.wbias[j];
                        #pragma unroll
                        for (int r = 0; r < 4; ++r) {
                            int i = i0 + quad * 4 + r;
                            if (i < a.N) a.h2[(long)i * Mp + j] = f2bf((acc[q][r] + wb) * a.dinv[i]);
                        }
                    }
                }
            }
        }
        grid.sync();

        if (l < 4) {
            // ---- agg + fused stats phase ----
            {
                const int M = dimOf(l + 1);
                const int hs = (M + 15) & ~15;
                const int ts = (M + 31) & ~31;
                const int Q = ts >> 2;
                const int rpb = 256 / Q;
                for (int j = tid; j < 2 * ts; j += 256) smf[j] = 0.f;
                __syncthreads();
                const int slot = tid / Q;
                const int jp = tid - slot * Q;
                const bool act = slot < rpb;
                const int j0 = jp << 2;
                float S0 = 0, S1 = 0, S2 = 0, S3 = 0, T0 = 0, T1 = 0, T2 = 0, T3 = 0;
                const int rowsPerGrid = nb * rpb;
                const int nIt = (a.N + rowsPerGrid - 1) / rowsPerGrid;
                const float* bb = selB(a, l);
                for (int it = 0; it < nIt; ++it) {
                    int i = (it * nb + bid) * rpb + slot;
                    if (act && i < a.N) {
                        float r0 = 0.f, r1 = 0.f, r2 = 0.f, r3 = 0.f;
                        if (j0 < M) {
                            const int s0 = a.row_start[i], s1 = a.row_start[i + 1];
                            const ushort_t* hp = a.h2 + j0;
                            uint2 v = *(const uint2*)(hp + (long)i * hs);
                            float a0 = bf2f((ushort_t)(v.x & 0xffff)), a1 = bf2f((ushort_t)(v.x >> 16));
                            float a2 = bf2f((ushort_t)(v.y & 0xffff)), a3 = bf2f((ushort_t)(v.y >> 16));
                            int e = s0;
                            for (; e + 3 < s1; e += 4) {
                                int n0 = a.csr_src[e], n1 = a.csr_src[e + 1];
                                int n2 = a.csr_src[e + 2], n3 = a.csr_src[e + 3];
                                uint2 w0 = *(const uint2*)(hp + (long)n0 * hs);
                                uint2 w1 = *(const uint2*)(hp + (long)n1 * hs);
                                uint2 w2 = *(const uint2*)(hp + (long)n2 * hs);
                                uint2 w3 = *(const uint2*)(hp + (long)n3 * hs);
                                a0 += bf2f((ushort_t)(w0.x & 0xffff)); a1 += bf2f((ushort_t)(w0.x >> 16));
                                a2 += bf2f((ushort_t)(w0.y & 0xffff)); a3 += bf2f((ushort_t)(w0.y >> 16));
                                a0 += bf2f((ushort_t)(w1.x & 0xffff)); a1 += bf2f((ushort_t)(w1.x >> 16));
                                a2 += bf2f((ushort_t)(w1.y & 0xffff)); a3 += bf2f((ushort_t)(w1.y >> 16));
                                a0 += bf2f((ushort_t)(w2.x & 0xffff)); a1 += bf2f((ushort_t)(w2.x >> 16));
                                a2 += bf2f((ushort_t)(w2.y & 0xffff)); a3 += bf2f((ushort_t)(w2.y >> 16));
                                a0 += bf2f((ushort_t)(w3.x & 0xffff)); a1 += bf2f((ushort_t)(w3.x >> 16));
                                a2 += bf2f((ushort_t)(w3.y & 0xffff)); a3 += bf2f((ushort_t)(w3.y >> 16));
                            }
                            for (; e < s1; ++e) {
                                uint2 w = *(const uint2*)(hp + (long)a.csr_src[e] * hs);
                                a0 += bf2f((ushort_t)(w.x & 0xffff)); a1 += bf2f((ushort_t)(w.x >> 16));
                                a2 += bf2f((ushort_t)(w.y & 0xffff)); a3 += bf2f((ushort_t)(w.y >> 16));
                            }
                            const float di = a.dinv[i];
                            r0 = fmaxf(a0 * di + bb[j0], 0.f);
                            r1 = (j0 + 1 < M) ? fmaxf(a1 * di + bb[j0 + 1], 0.f) : 0.f;
                            r2 = (j0 + 2 < M) ? fmaxf(a2 * di + bb[j0 + 2], 0.f) : 0.f;
                            r3 = (j0 + 3 < M) ? fmaxf(a3 * di + bb[j0 + 3], 0.f) : 0.f;
                        }
                        uint2 pk;
                        pk.x = (uint_t)f2bf(r0) | ((uint_t)f2bf(r1) << 16);
                        pk.y = (uint_t)f2bf(r2) | ((uint_t)f2bf(r3) << 16);
                        *(uint2*)(a.tmpb + (long)i * ts + j0) = pk;
                        S0 += r0; T0 += r0 * r0; S1 += r1; T1 += r1 * r1;
                        S2 += r2; T2 += r2 * r2; S3 += r3; T3 += r3 * r3;
                    }
                }
                if (act) {
                    atomicAdd(&smf[j0], S0);     atomicAdd(&smf[j0 + 1], S1);
                    atomicAdd(&smf[j0 + 2], S2); atomicAdd(&smf[j0 + 3], S3);
                    atomicAdd(&smf[ts + j0], T0);     atomicAdd(&smf[ts + j0 + 1], T1);
                    atomicAdd(&smf[ts + j0 + 2], T2); atomicAdd(&smf[ts + j0 + 3], T3);
                }
                __syncthreads();
                float* cs = a.stats + l * 512;
                float* cq = cs + 256;
                for (int j = tid; j < M; j += 256) {
                    atomicAdd(&cs[j], smf[j]);
                    atomicAdd(&cq[j], smf[ts + j]);
                }
            }
            grid.sync();

            // ---- prep(l+1): fold BN(l) affine into Wt, wbias ----
            {
                const int lp = l + 1;
                const int K = dimOf(lp), M = dimOf(lp + 1);
                const int Kp = (K + 31) & ~31, Mp = (M + 15) & ~15;
                if (tid < K) {
                    const float* cs = a.stats + l * 512;
                    const float* cq = cs + 256;
                    const float invN = 1.f / (float)a.N;
                    float mu = cs[tid] * invN;
                    float var = cq[tid] * invN - mu * mu;
                    float sc = selG(a, l)[tid] * rsqrtf(var + 1e-5f);
                    float sh = selE(a, l)[tid] - mu * sc;
                    smf[tid] = sc; smf[256 + tid] = sh;
                }
                __syncthreads();
                const float* W = selW(a, lp);
                const long tot = (long)Mp * Kp;
                for (long idx = gt; idx < tot; idx += gthreads) {
                    int j = (int)(idx / Kp);
                    int k = (int)(idx - (long)j * Kp);
                    float v = 0.f;
                    if (k < K && j < M) v = smf[k] * W[(long)k * M + j];
                    a.Wt[idx] = f2bf(v);
                }
                for (int u = gt; u < 4 * Mp; u += gthreads) {
                    int j = u >> 2, kg = u & 3;
                    float s = 0.f;
                    if (j < M) {
                        for (int k = kg; k < K; k += 4) s += smf[256 + k] * W[(long)k * M + j];
                    }
                    s += __shfl_xor(s, 1, 64);
                    s += __shfl_xor(s, 2, 64);
                    if (kg == 0) a.wbias[j] = s;
                }
            }
            grid.sync();
        } else {
            // ---- final: gather + bias + log_softmax ----
            const int M = 17;
            const int x16 = tid & 15;
            const int rslot = tid >> 4;
            const int j0 = 2 * x16, j1 = j0 + 1;
            const int rowsPerGrid = nb * 16;
            const int nIt = (a.N + rowsPerGrid - 1) / rowsPerGrid;
            for (int it = 0; it < nIt; ++it) {
                int i = (it * nb + bid) * 16 + rslot;
                if (i < a.N) {
                    uint_t v = *(const uint_t*)(a.h2 + (long)i * 32 + j0);
                    float a0 = bf2f((ushort_t)(v & 0xffff));
                    float a1 = bf2f((ushort_t)(v >> 16));
                    const int s0 = a.row_start[i], s1 = a.row_start[i + 1];
                    int e = s0;
                    for (; e + 1 < s1; e += 2) {
                        int n0 = a.csr_src[e], n1 = a.csr_src[e + 1];
                        uint_t w0 = *(const uint_t*)(a.h2 + (long)n0 * 32 + j0);
                        uint_t w1 = *(const uint_t*)(a.h2 + (long)n1 * 32 + j0);
                        a0 += bf2f((ushort_t)(w0 & 0xffff)); a1 += bf2f((ushort_t)(w0 >> 16));
                        a0 += bf2f((ushort_t)(w1 & 0xffff)); a1 += bf2f((ushort_t)(w1 >> 16));
                    }
                    for (; e < s1; ++e) {
                        uint_t w = *(const uint_t*)(a.h2 + (long)a.csr_src[e] * 32 + j0);
                        a0 += bf2f((ushort_t)(w & 0xffff)); a1 += bf2f((ushort_t)(w >> 16));
                    }
                    const float di = a.dinv[i];
                    float r0 = (j0 < M) ? (a0 * di + a.b4[j0]) : -INFINITY;
                    float r1 = (j1 < M) ? (a1 * di + a.b4[j1]) : -INFINITY;
                    float m = fmaxf(r0, r1);
                    #pragma unroll
                    for (int msk = 1; msk < 16; msk <<= 1) m = fmaxf(m, __shfl_xor(m, msk, 16));
                    float s = ((j0 < M) ? expf(r0 - m) : 0.f) + ((j1 < M) ? expf(r1 - m) : 0.f);
                    #pragma unroll
                    for (int msk = 1; msk < 16; msk <<= 1) s += __shfl_xor(s, msk, 16);
                    const float lg = logf(s) + m;
                    if (j0 < M) a.out[(long)i * M + j0] = r0 - lg;
                    if (j1 < M) a.out[(long)i * M + j1] = r1 - lg;
                }
            }
        }
    }
}

// ---------------- launch ----------------

extern "C" void kernel_launch(void* const* d_in, const int* in_sizes, int n_in,
                              void* d_out, int out_size, void* d_ws, size_t ws_size,
                              hipStream_t stream)
{
    const int N = in_sizes[0] / 256;   // 10000
    const int E = in_sizes[1] / 2;     // 320000

    GArgs a;
    a.x    = (const float*)d_in[0];
    a.srcv = (const int*)d_in[1];
    a.dstv = ((const int*)d_in[1]) + E;
    a.W0 = (const float*)d_in[2];  a.b0 = (const float*)d_in[3];
    a.W1 = (const float*)d_in[4];  a.b1 = (const float*)d_in[5];
    a.W2 = (const float*)d_in[6];  a.b2 = (const float*)d_in[7];
    a.W3 = (const float*)d_in[8];  a.b3 = (const float*)d_in[9];
    a.W4 = (const float*)d_in[10]; a.b4 = (const float*)d_in[11];
    a.g0 = (const float*)d_in[12]; a.e0 = (const float*)d_in[13];
    a.g1 = (const float*)d_in[14]; a.e1 = (const float*)d_in[15];
    a.g2 = (const float*)d_in[16]; a.e2 = (const float*)d_in[17];
    a.g3 = (const float*)d_in[18]; a.e3 = (const float*)d_in[19];
    a.out = (float*)d_out;

    char* w = (char*)d_ws;
    const long NB  = ((long)N * 4 + 255) & ~255L;
    const long NB1 = ((long)(N + 1) * 4 + 255) & ~255L;
    const long EB  = ((long)E * 4 + 255) & ~255L;
    const long XBB = ((long)N * 256 * 2 + 255) & ~255L;
    const long FBB = ((long)N * 224 * 2 + 255) & ~255L;
    const long WTB = ((long)224 * 256 * 2 + 255) & ~255L;

    long o = 0;
    a.cnt       = (int*)(w + o);      o += NB;
    a.row_start = (int*)(w + o);      o += NB1;
    a.cursor    = (int*)(w + o);      o += NB;
    a.csr_src   = (int*)(w + o);      o += EB;
    a.dinv      = (float*)(w + o);    o += NB;
    a.stats     = (float*)(w + o);    o += 5 * 512 * 4;
    a.wbias     = (float*)(w + o);    o += 1024;
    a.xb        = (ushort_t*)(w + o); o += XBB;
    a.Wt        = (ushort_t*)(w + o); o += WTB;
    a.h2        = (ushort_t*)(w + o); o += FBB;
    a.tmpb      = (ushort_t*)(w + o); o += FBB;
    a.N = N;
    a.E = E;

    int perCU = 0;
    if (hipOccupancyMaxActiveBlocksPerMultiprocessor(&perCU, (const void*)k_mega, 256, 0)
            != hipSuccess || perCU < 1)
        perCU = 2;
    if (perCU > 4) perCU = 4;
    int grid = 256 * perCU;            // MI355X: 256 CUs
    if (grid > 1024) grid = 1024;

    void* params[] = { (void*)&a };
    hipLaunchCooperativeKernel((const void*)k_mega, dim3(grid), dim3(256),
                               params, 0, stream);
}

// Round 8
// 652.883 us; speedup vs baseline: 2.6917x; 2.6917x over previous
//
#include <hip/hip_runtime.h>
#include <math.h>

typedef unsigned short ushort_t;
typedef unsigned int uint_t;
typedef unsigned long long ull_t;

__device__ __forceinline__ float bf2f(ushort_t u) {
    union { uint_t i; float f; } x; x.i = ((uint_t)u) << 16; return x.f;
}
__device__ __forceinline__ ushort_t f2bf(float f) {
    union { float f; uint_t i; } x; x.f = f;
    uint_t r = x.i + 0x7FFFu + ((x.i >> 16) & 1u);
    return (ushort_t)(r >> 16);
}

// ---------------- init: zero cnt/stats/ctr/wbias + cvtx + prep layer 0 ----------------
__global__ __launch_bounds__(256) void k_init(
    const float* __restrict__ x, const float* __restrict__ W0,
    int* __restrict__ cnt, float* __restrict__ stats, int* __restrict__ ctr,
    float* __restrict__ wbias, ushort_t* __restrict__ xb, ushort_t* __restrict__ Wt,
    int N)
{
    const int gt = blockIdx.x * 256 + threadIdx.x;
    const int gth = gridDim.x * 256;
    for (int i = gt; i < N; i += gth) cnt[i] = 0;
    for (int i = gt; i < 2048; i += gth) stats[i] = 0.f;
    if (gt < 8) ctr[gt] = 0;
    if (gt < 256) wbias[gt] = 0.f;          // layer-0 wbias = 0
    const int n4 = N * 64;
    for (int i = gt; i < n4; i += gth) {
        float4 v = ((const float4*)x)[i];
        ushort_t* o = xb + i * 4;
        o[0] = f2bf(v.x); o[1] = f2bf(v.y); o[2] = f2bf(v.z); o[3] = f2bf(v.w);
    }
    // prep0: Wt[j][k] = bf16(W0[k][j]); Kp=256, Mp=224, K=256, M=220
    for (int idx = gt; idx < 224 * 256; idx += gth) {
        int j = idx >> 8;
        int k = idx & 255;
        float v = (j < 220) ? W0[(long)k * 220 + j] : 0.f;
        Wt[idx] = f2bf(v);
    }
}

__global__ void k_hist(const int* __restrict__ dst, int* __restrict__ cnt, int E) {
    int e = blockIdx.x * blockDim.x + threadIdx.x;
    if (e < E) atomicAdd(&cnt[dst[e]], 1);
}

__global__ __launch_bounds__(1024) void k_scan(
    const int* __restrict__ cnt, int* __restrict__ row_start,
    int* __restrict__ cursor, float* __restrict__ dinv, int N)
{
    __shared__ int sh[1024];
    const int tid = threadIdx.x;
    const int chunk = (N + 1023) >> 10;
    int loc[16];
    const int base = tid * chunk;
    int sum = 0;
    for (int c = 0; c < chunk; ++c) {
        int i = base + c;
        int v = (i < N) ? cnt[i] : 0;
        loc[c] = sum;
        sum += v;
    }
    sh[tid] = sum;
    __syncthreads();
    for (int off = 1; off < 1024; off <<= 1) {
        int v = (tid >= off) ? sh[tid - off] : 0;
        __syncthreads();
        sh[tid] += v;
        __syncthreads();
    }
    const int excl = sh[tid] - sum;
    for (int c = 0; c < chunk; ++c) {
        int i = base + c;
        if (i < N) {
            int rs = excl + loc[c];
            row_start[i] = rs;
            cursor[i] = rs;
            dinv[i] = rsqrtf(1.0f + (float)cnt[i]);
        }
    }
    if (tid == 1023) row_start[N] = sh[1023];
}

__global__ void k_fill(const int* __restrict__ src, const int* __restrict__ dst,
                       int* __restrict__ cursor, int* __restrict__ csr_src, int E) {
    int e = blockIdx.x * blockDim.x + threadIdx.x;
    if (e < E) {
        int pos = atomicAdd(&cursor[dst[e]], 1);
        csr_src[pos] = src[e];
    }
}

// ---------------- fused prep: Wt (scale-folded transpose) + wbias ----------------
// grid: ( ceil(Kp/64), yW+1 ), block (64,4). Rows y<yW do Wt; y==yW does wbias.
__global__ void k_prep(const float* __restrict__ W,
                       const float* __restrict__ scl, const float* __restrict__ shf,
                       ushort_t* __restrict__ Wt, float* __restrict__ wbias,
                       int K, int M, int Kp, int Mp, int yW)
{
    if ((int)blockIdx.y < yW) {
        int k = blockIdx.x * 64 + threadIdx.x;
        int j = blockIdx.y * 4 + threadIdx.y;
        if (k >= Kp || j >= Mp) return;
        float v = 0.f;
        if (k < K && j < M) v = scl[k] * W[(long)k * M + j];
        Wt[(long)j * Kp + k] = f2bf(v);
    } else {
        __shared__ float red[4][64];
        int t = threadIdx.y * 64 + threadIdx.x;
        int jl = t & 63, kg = t >> 6;
        int j = blockIdx.x * 64 + jl;
        float s = 0.f;
        if (j < M) {
            for (int k = kg; k < K; k += 4) s += shf[k] * W[(long)k * M + j];
        }
        red[kg][jl] = s;
        __syncthreads();
        if (kg == 0 && j < Mp) wbias[j] = red[0][jl] + red[1][jl] + red[2][jl] + red[3][jl];
    }
}

// ---------------- MFMA GEMM (unchanged from R6) ----------------
template<int KP>
__global__ __launch_bounds__(64) void k_gemm_mfma(
    const ushort_t* __restrict__ Xb, const ushort_t* __restrict__ Wt,
    const float* __restrict__ wbias, const float* __restrict__ dinv,
    ushort_t* __restrict__ h2, int N, int Mp)
{
    typedef __attribute__((ext_vector_type(8))) short short8;
    typedef __attribute__((ext_vector_type(4))) float floatx4;
    const int lane = threadIdx.x;
    const int m = lane & 15;
    const int quad = lane >> 4;
    const int i0 = blockIdx.x * 16;
    const int j0 = blockIdx.y * 64;
    const int ntiles = min(4, (Mp - j0) >> 4);

    floatx4 acc[4];
    #pragma unroll
    for (int t = 0; t < 4; ++t) { acc[t].x = 0.f; acc[t].y = 0.f; acc[t].z = 0.f; acc[t].w = 0.f; }

    const int ra = min(i0 + m, N - 1);
    const ushort_t* arow = Xb + (long)ra * KP + quad * 8;
    const ushort_t* brow = Wt + (long)(j0 + m) * KP + quad * 8;

    #pragma unroll
    for (int k0 = 0; k0 < KP; k0 += 32) {
        short8 av = *(const short8*)(arow + k0);
        #pragma unroll
        for (int t = 0; t < 4; ++t) {
            if (t < ntiles) {
                short8 bv = *(const short8*)(brow + (long)t * 16 * KP + k0);
                acc[t] = __builtin_amdgcn_mfma_f32_16x16x32_bf16(av, bv, acc[t], 0, 0, 0);
            }
        }
    }

    #pragma unroll
    for (int t = 0; t < 4; ++t) {
        if (t < ntiles) {
            int j = j0 + t * 16 + m;
            float wb = wbias[j];
            #pragma unroll
            for (int r = 0; r < 4; ++r) {
                int i = i0 + quad * 4 + r;
                if (i < N) h2[(long)i * Mp + j] = f2bf((acc[t][r] + wb) * dinv[i]);
            }
        }
    }
}

// ---------------- agg + fused stats + last-block BN finalize ----------------
__global__ __launch_bounds__(256) void k_aggstat(
    const int* __restrict__ row_start, const int* __restrict__ csr_src,
    const ushort_t* __restrict__ h2, int hs,
    const float* __restrict__ dinv, const float* __restrict__ b,
    ushort_t* __restrict__ tmpb, int ts,
    const float* __restrict__ g, const float* __restrict__ be,
    float* __restrict__ cs, float* __restrict__ cq, int* __restrict__ ctr,
    float* __restrict__ scl, float* __restrict__ shf,
    int N, int M, int Q, ull_t magic, uint_t sh, float invN)
{
    __shared__ float sred[448];
    __shared__ int lastflag;
    const int tid = threadIdx.x;
    for (int j = tid; j < 2 * ts; j += 256) sred[j] = 0.f;
    __syncthreads();

    const uint_t gidx = blockIdx.x * 256 + tid;
    const uint_t i = (uint_t)(((ull_t)gidx * magic) >> sh);
    const int jp = (int)(gidx - i * Q);
    const int j0 = jp << 2;
    const bool active = (i < (uint_t)N);
    if (active) {
        if (j0 >= M) {
            *(uint2*)(tmpb + (long)i * ts + j0) = make_uint2(0u, 0u);
        } else {
            const int s0 = row_start[i], s1 = row_start[i + 1];
            const ushort_t* hp = h2 + j0;
            uint2 v = *(const uint2*)(hp + (long)i * hs);
            float a0 = bf2f((ushort_t)(v.x & 0xffff)), a1 = bf2f((ushort_t)(v.x >> 16));
            float a2 = bf2f((ushort_t)(v.y & 0xffff)), a3 = bf2f((ushort_t)(v.y >> 16));
            int e = s0;
            for (; e + 3 < s1; e += 4) {
                int n0 = csr_src[e], n1 = csr_src[e + 1], n2 = csr_src[e + 2], n3 = csr_src[e + 3];
                uint2 w0 = *(const uint2*)(hp + (long)n0 * hs);
                uint2 w1 = *(const uint2*)(hp + (long)n1 * hs);
                uint2 w2 = *(const uint2*)(hp + (long)n2 * hs);
                uint2 w3 = *(const uint2*)(hp + (long)n3 * hs);
                a0 += bf2f((ushort_t)(w0.x & 0xffff)); a1 += bf2f((ushort_t)(w0.x >> 16));
                a2 += bf2f((ushort_t)(w0.y & 0xffff)); a3 += bf2f((ushort_t)(w0.y >> 16));
                a0 += bf2f((ushort_t)(w1.x & 0xffff)); a1 += bf2f((ushort_t)(w1.x >> 16));
                a2 += bf2f((ushort_t)(w1.y & 0xffff)); a3 += bf2f((ushort_t)(w1.y >> 16));
                a0 += bf2f((ushort_t)(w2.x & 0xffff)); a1 += bf2f((ushort_t)(w2.x >> 16));
                a2 += bf2f((ushort_t)(w2.y & 0xffff)); a3 += bf2f((ushort_t)(w2.y >> 16));
                a0 += bf2f((ushort_t)(w3.x & 0xffff)); a1 += bf2f((ushort_t)(w3.x >> 16));
                a2 += bf2f((ushort_t)(w3.y & 0xffff)); a3 += bf2f((ushort_t)(w3.y >> 16));
            }
            for (; e < s1; ++e) {
                uint2 w = *(const uint2*)(hp + (long)csr_src[e] * hs);
                a0 += bf2f((ushort_t)(w.x & 0xffff)); a1 += bf2f((ushort_t)(w.x >> 16));
                a2 += bf2f((ushort_t)(w.y & 0xffff)); a3 += bf2f((ushort_t)(w.y >> 16));
            }
            const float di = dinv[i];
            float r0 = fmaxf(a0 * di + b[j0], 0.f);
            float r1 = (j0 + 1 < M) ? fmaxf(a1 * di + b[j0 + 1], 0.f) : 0.f;
            float r2 = (j0 + 2 < M) ? fmaxf(a2 * di + b[j0 + 2], 0.f) : 0.f;
            float r3 = (j0 + 3 < M) ? fmaxf(a3 * di + b[j0 + 3], 0.f) : 0.f;
            uint2 pk;
            pk.x = (uint_t)f2bf(r0) | ((uint_t)f2bf(r1) << 16);
            pk.y = (uint_t)f2bf(r2) | ((uint_t)f2bf(r3) << 16);
            *(uint2*)(tmpb + (long)i * ts + j0) = pk;
            atomicAdd(&sred[j0], r0);          atomicAdd(&sred[ts + j0], r0 * r0);
            atomicAdd(&sred[j0 + 1], r1);      atomicAdd(&sred[ts + j0 + 1], r1 * r1);
            atomicAdd(&sred[j0 + 2], r2);      atomicAdd(&sred[ts + j0 + 2], r2 * r2);
            atomicAdd(&sred[j0 + 3], r3);      atomicAdd(&sred[ts + j0 + 3], r3 * r3);
        }
    }
    __syncthreads();
    for (int j = tid; j < M; j += 256) {
        atomicAdd(&cs[j], sred[j]);
        atomicAdd(&cq[j], sred[ts + j]);
    }
    __threadfence();
    __syncthreads();
    if (tid == 0) lastflag = (atomicAdd(ctr, 1) == (int)gridDim.x - 1) ? 1 : 0;
    __syncthreads();
    if (lastflag) {
        // device-scope atomic reads (cross-XCD safe), then finalize BN affine
        if (tid < M) {
            float csv = atomicAdd(&cs[tid], 0.f);
            float cqv = atomicAdd(&cq[tid], 0.f);
            float mu = csv * invN;
            float var = cqv * invN - mu * mu;
            float sc = g[tid] * rsqrtf(var + 1e-5f);
            scl[tid] = sc;
            shf[tid] = be[tid] - mu * sc;
        }
    }
}

// ---------------- final layer: gather + bias + log_softmax ----------------
__global__ __launch_bounds__(256) void k_agg_final(
    const int* __restrict__ row_start, const int* __restrict__ csr_src,
    const ushort_t* __restrict__ h2, const float* __restrict__ dinv,
    const float* __restrict__ b, float* __restrict__ out, int N, int M)
{
    const int x = threadIdx.x;                 // 0..15
    const int i = blockIdx.x * 16 + threadIdx.y;
    if (i >= N) return;
    const int j0 = 2 * x, j1 = 2 * x + 1;
    uint_t v = *(const uint_t*)(h2 + (long)i * 32 + j0);
    float a0 = bf2f((ushort_t)(v & 0xffff));
    float a1 = bf2f((ushort_t)(v >> 16));
    const int s0 = row_start[i];
    const int s1 = row_start[i + 1];
    int e = s0;
    for (; e + 1 < s1; e += 2) {
        int n0 = csr_src[e], n1 = csr_src[e + 1];
        uint_t w0 = *(const uint_t*)(h2 + (long)n0 * 32 + j0);
        uint_t w1 = *(const uint_t*)(h2 + (long)n1 * 32 + j0);
        a0 += bf2f((ushort_t)(w0 & 0xffff)); a1 += bf2f((ushort_t)(w0 >> 16));
        a0 += bf2f((ushort_t)(w1 & 0xffff)); a1 += bf2f((ushort_t)(w1 >> 16));
    }
    for (; e < s1; ++e) {
        uint_t w = *(const uint_t*)(h2 + (long)csr_src[e] * 32 + j0);
        a0 += bf2f((ushort_t)(w & 0xffff)); a1 += bf2f((ushort_t)(w >> 16));
    }
    const float di = dinv[i];
    float r0 = (j0 < M) ? (a0 * di + b[j0]) : -INFINITY;
    float r1 = (j1 < M) ? (a1 * di + b[j1]) : -INFINITY;
    float m = fmaxf(r0, r1);
    #pragma unroll
    for (int msk = 1; msk < 16; msk <<= 1) m = fmaxf(m, __shfl_xor(m, msk, 16));
    float s = ((j0 < M) ? expf(r0 - m) : 0.f) + ((j1 < M) ? expf(r1 - m) : 0.f);
    #pragma unroll
    for (int msk = 1; msk < 16; msk <<= 1) s += __shfl_xor(s, msk, 16);
    const float l = logf(s) + m;
    if (j0 < M) out[(long)i * M + j0] = r0 - l;
    if (j1 < M) out[(long)i * M + j1] = r1 - l;
}

// ---------------- launch ----------------

static inline int pad16(int v) { return (v + 15) & ~15; }
static inline int pad32(int v) { return (v + 31) & ~31; }

extern "C" void kernel_launch(void* const* d_in, const int* in_sizes, int n_in,
                              void* d_out, int out_size, void* d_ws, size_t ws_size,
                              hipStream_t stream)
{
    const int dims[6] = {256, 220, 150, 100, 60, 17};
    const int N = in_sizes[0] / dims[0];      // 10000
    const int E = in_sizes[1] / 2;            // 320000

    const float* x  = (const float*)d_in[0];
    const int* ei   = (const int*)d_in[1];
    const int* srcv = ei;
    const int* dstv = ei + E;
    const float* Wl[5], *bl[5];
    for (int l = 0; l < 5; ++l) {
        Wl[l] = (const float*)d_in[2 + 2 * l];
        bl[l] = (const float*)d_in[3 + 2 * l];
    }
    const float* gl[4], *bel[4];
    for (int l = 0; l < 4; ++l) {
        gl[l]  = (const float*)d_in[12 + 2 * l];
        bel[l] = (const float*)d_in[13 + 2 * l];
    }
    float* out = (float*)d_out;

    // ---- workspace layout ----
    char* w = (char*)d_ws;
    const long NB  = ((long)N * 4 + 255) & ~255L;
    const long NB1 = ((long)(N + 1) * 4 + 255) & ~255L;
    const long EB  = ((long)E * 4 + 255) & ~255L;
    const long XBB = ((long)N * 256 * 2 + 255) & ~255L;
    const long FBB = ((long)N * 224 * 2 + 255) & ~255L;
    const long WTB = ((long)224 * 256 * 2 + 255) & ~255L;

    long o = 0;
    float* dinv      = (float*)(w + o);  o += NB;
    float* stats     = (float*)(w + o);  o += 2048 * 4;   // 4 layers x (cs[256]+cq[256])
    float* scl       = (float*)(w + o);  o += 1024;
    float* shf       = (float*)(w + o);  o += 1024;
    float* wbias     = (float*)(w + o);  o += 1024;
    int*   ctr       = (int*)(w + o);    o += 256;
    int*   cnt       = (int*)(w + o);    o += NB;
    int*   row_start = (int*)(w + o);    o += NB1;
    int*   cursor    = (int*)(w + o);    o += NB;
    int*   csr_src   = (int*)(w + o);    o += EB;
    ushort_t* xb     = (ushort_t*)(w + o); o += XBB;
    ushort_t* Wt     = (ushort_t*)(w + o); o += WTB;
    ushort_t* h2     = (ushort_t*)(w + o); o += FBB;
    ushort_t* tmpb   = (ushort_t*)(w + o); o += FBB;

    const int eBlk = (E + 255) / 256;
    const float invN = 1.0f / (float)N;

    k_init<<<(N * 64 + 255) / 256, 256, 0, stream>>>(x, Wl[0], cnt, stats, ctr,
                                                     wbias, xb, Wt, N);
    k_hist<<<eBlk, 256, 0, stream>>>(dstv, cnt, E);
    k_scan<<<1, 1024, 0, stream>>>(cnt, row_start, cursor, dinv, N);
    k_fill<<<eBlk, 256, 0, stream>>>(srcv, dstv, cursor, csr_src, E);

    for (int l = 0; l < 5; ++l) {
        const int K  = dims[l];
        const int M  = dims[l + 1];
        const int Kp = pad32(K);
        const int Mp = pad16(M);
        const int ts = (l < 4) ? pad32(M) : 32;
        const ushort_t* X = (l == 0) ? xb : tmpb;

        if (l > 0) {
            const int yW = (Mp + 3) / 4;
            k_prep<<<dim3((Kp + 63) / 64, yW + 1), dim3(64, 4), 0, stream>>>(
                Wl[l], scl, shf, Wt, wbias, K, M, Kp, Mp, yW);
        }

        dim3 gg((N + 15) / 16, (Mp + 63) / 64);
        switch (Kp) {
            case 256: k_gemm_mfma<256><<<gg, 64, 0, stream>>>(X, Wt, wbias, dinv, h2, N, Mp); break;
            case 224: k_gemm_mfma<224><<<gg, 64, 0, stream>>>(X, Wt, wbias, dinv, h2, N, Mp); break;
            case 160: k_gemm_mfma<160><<<gg, 64, 0, stream>>>(X, Wt, wbias, dinv, h2, N, Mp); break;
            case 128: k_gemm_mfma<128><<<gg, 64, 0, stream>>>(X, Wt, wbias, dinv, h2, N, Mp); break;
            case  64: k_gemm_mfma< 64><<<gg, 64, 0, stream>>>(X, Wt, wbias, dinv, h2, N, Mp); break;
        }

        if (l < 4) {
            const int Q = ts / 4;
            uint_t shmt = 0;
            while ((1u << shmt) < (uint_t)Q) ++shmt;
            shmt += 32;
            const ull_t magic = ((1ULL << shmt) + Q - 1) / (ull_t)Q;   // 64-bit! (pow2 Q)
            const long total = (long)N * Q;
            k_aggstat<<<(int)((total + 255) / 256), 256, 0, stream>>>(
                row_start, csr_src, h2, Mp, dinv, bl[l], tmpb, ts,
                gl[l], bel[l], stats + l * 512, stats + l * 512 + 256, ctr + l,
                scl, shf, N, M, Q, magic, shmt, invN);
        } else {
            k_agg_final<<<(N + 15) / 16, dim3(16, 16), 0, stream>>>(
                row_start, csr_src, h2, dinv, bl[l], out, N, M);
        }
    }
}

// Round 9
// 412.894 us; speedup vs baseline: 4.2562x; 1.5812x over previous
//
#include <hip/hip_runtime.h>
#include <math.h>

typedef unsigned short ushort_t;
typedef unsigned int uint_t;
typedef unsigned long long ull_t;

__device__ __forceinline__ float bf2f(ushort_t u) {
    union { uint_t i; float f; } x; x.i = ((uint_t)u) << 16; return x.f;
}
__device__ __forceinline__ ushort_t f2bf(float f) {
    union { float f; uint_t i; } x; x.f = f;
    uint_t r = x.i + 0x7FFFu + ((x.i >> 16) & 1u);
    return (ushort_t)(r >> 16);
}

// ---------------- init: zero cnt/stats + cvtx + prep layer 0 ----------------
__global__ __launch_bounds__(256) void k_init(
    const float* __restrict__ x, const float* __restrict__ W0,
    int* __restrict__ cnt, float* __restrict__ stats,
    float* __restrict__ wbias, ushort_t* __restrict__ xb, ushort_t* __restrict__ Wt,
    int N)
{
    const int gt = blockIdx.x * 256 + threadIdx.x;
    const int gth = gridDim.x * 256;
    for (int i = gt; i < N; i += gth) cnt[i] = 0;
    for (int i = gt; i < 2048; i += gth) stats[i] = 0.f;
    if (gt < 256) wbias[gt] = 0.f;          // layer-0 wbias = 0
    const int n4 = N * 64;
    for (int i = gt; i < n4; i += gth) {
        float4 v = ((const float4*)x)[i];
        ushort_t* o = xb + i * 4;
        o[0] = f2bf(v.x); o[1] = f2bf(v.y); o[2] = f2bf(v.z); o[3] = f2bf(v.w);
    }
    // prep0: Wt[j][k] = bf16(W0[k][j]); Kp=256, Mp=224, K=256, M=220
    for (int idx = gt; idx < 224 * 256; idx += gth) {
        int j = idx >> 8;
        int k = idx & 255;
        float v = (j < 220) ? W0[(long)k * 220 + j] : 0.f;
        Wt[idx] = f2bf(v);
    }
}

__global__ void k_hist(const int* __restrict__ dst, int* __restrict__ cnt, int E) {
    int e = blockIdx.x * blockDim.x + threadIdx.x;
    if (e < E) atomicAdd(&cnt[dst[e]], 1);
}

__global__ __launch_bounds__(1024) void k_scan(
    const int* __restrict__ cnt, int* __restrict__ row_start,
    int* __restrict__ cursor, float* __restrict__ dinv, int N)
{
    __shared__ int sh[1024];
    const int tid = threadIdx.x;
    const int chunk = (N + 1023) >> 10;
    int loc[16];
    const int base = tid * chunk;
    int sum = 0;
    for (int c = 0; c < chunk; ++c) {
        int i = base + c;
        int v = (i < N) ? cnt[i] : 0;
        loc[c] = sum;
        sum += v;
    }
    sh[tid] = sum;
    __syncthreads();
    for (int off = 1; off < 1024; off <<= 1) {
        int v = (tid >= off) ? sh[tid - off] : 0;
        __syncthreads();
        sh[tid] += v;
        __syncthreads();
    }
    const int excl = sh[tid] - sum;
    for (int c = 0; c < chunk; ++c) {
        int i = base + c;
        if (i < N) {
            int rs = excl + loc[c];
            row_start[i] = rs;
            cursor[i] = rs;
            dinv[i] = rsqrtf(1.0f + (float)cnt[i]);
        }
    }
    if (tid == 1023) row_start[N] = sh[1023];
}

__global__ void k_fill(const int* __restrict__ src, const int* __restrict__ dst,
                       int* __restrict__ cursor, int* __restrict__ csr_src, int E) {
    int e = blockIdx.x * blockDim.x + threadIdx.x;
    if (e < E) {
        int pos = atomicAdd(&cursor[dst[e]], 1);
        csr_src[pos] = src[e];
    }
}

// ---------------- fused prep: BN finalize (from stats) + Wt fold + wbias ----------------
// grid: ( ceil(Kp/64), yW+1 ), block (64,4). blockIdx.y < yW: Wt; == yW: wbias.
__global__ void k_prep(const float* __restrict__ W,
                       const float* __restrict__ g, const float* __restrict__ be,
                       const float* __restrict__ cs, const float* __restrict__ cq,
                       ushort_t* __restrict__ Wt, float* __restrict__ wbias,
                       int K, int M, int Kp, int Mp, int yW, float invN)
{
    __shared__ float sm[256];
    if ((int)blockIdx.y < yW) {
        // scale for this block's 64 k values
        if (threadIdx.y == 0) {
            int kk = blockIdx.x * 64 + threadIdx.x;
            float sc = 0.f;
            if (kk < K) {
                float mu = cs[kk] * invN;
                float var = cq[kk] * invN - mu * mu;
                sc = g[kk] * rsqrtf(var + 1e-5f);
            }
            sm[threadIdx.x] = sc;
        }
        __syncthreads();
        int k = blockIdx.x * 64 + threadIdx.x;
        int j = blockIdx.y * 4 + threadIdx.y;
        if (k >= Kp || j >= Mp) return;
        float v = 0.f;
        if (k < K && j < M) v = sm[threadIdx.x] * W[(long)k * M + j];
        Wt[(long)j * Kp + k] = f2bf(v);
    } else {
        __shared__ float red[4][64];
        int t = threadIdx.y * 64 + threadIdx.x;
        // shift for all K values, cooperatively
        for (int kk = t; kk < K; kk += 256) {
            float mu = cs[kk] * invN;
            float var = cq[kk] * invN - mu * mu;
            float sc = g[kk] * rsqrtf(var + 1e-5f);
            sm[kk] = be[kk] - mu * sc;
        }
        __syncthreads();
        int jl = t & 63, kg = t >> 6;
        int j = blockIdx.x * 64 + jl;
        float s = 0.f;
        if (j < M) {
            for (int k = kg; k < K; k += 4) s += sm[k] * W[(long)k * M + j];
        }
        red[kg][jl] = s;
        __syncthreads();
        if (kg == 0 && j < Mp) wbias[j] = red[0][jl] + red[1][jl] + red[2][jl] + red[3][jl];
    }
}

// ---------------- MFMA GEMM (R6, unchanged) ----------------
template<int KP>
__global__ __launch_bounds__(64) void k_gemm_mfma(
    const ushort_t* __restrict__ Xb, const ushort_t* __restrict__ Wt,
    const float* __restrict__ wbias, const float* __restrict__ dinv,
    ushort_t* __restrict__ h2, int N, int Mp)
{
    typedef __attribute__((ext_vector_type(8))) short short8;
    typedef __attribute__((ext_vector_type(4))) float floatx4;
    const int lane = threadIdx.x;
    const int m = lane & 15;
    const int quad = lane >> 4;
    const int i0 = blockIdx.x * 16;
    const int j0 = blockIdx.y * 64;
    const int ntiles = min(4, (Mp - j0) >> 4);

    floatx4 acc[4];
    #pragma unroll
    for (int t = 0; t < 4; ++t) { acc[t].x = 0.f; acc[t].y = 0.f; acc[t].z = 0.f; acc[t].w = 0.f; }

    const int ra = min(i0 + m, N - 1);
    const ushort_t* arow = Xb + (long)ra * KP + quad * 8;
    const ushort_t* brow = Wt + (long)(j0 + m) * KP + quad * 8;

    #pragma unroll
    for (int k0 = 0; k0 < KP; k0 += 32) {
        short8 av = *(const short8*)(arow + k0);
        #pragma unroll
        for (int t = 0; t < 4; ++t) {
            if (t < ntiles) {
                short8 bv = *(const short8*)(brow + (long)t * 16 * KP + k0);
                acc[t] = __builtin_amdgcn_mfma_f32_16x16x32_bf16(av, bv, acc[t], 0, 0, 0);
            }
        }
    }

    #pragma unroll
    for (int t = 0; t < 4; ++t) {
        if (t < ntiles) {
            int j = j0 + t * 16 + m;
            float wb = wbias[j];
            #pragma unroll
            for (int r = 0; r < 4; ++r) {
                int i = i0 + quad * 4 + r;
                if (i < N) h2[(long)i * Mp + j] = f2bf((acc[t][r] + wb) * dinv[i]);
            }
        }
    }
}

// ---------------- aggregation (R6, unchanged; 64-bit magic) ----------------
__global__ __launch_bounds__(256) void k_agg(
    const int* __restrict__ row_start, const int* __restrict__ csr_src,
    const ushort_t* __restrict__ h2, int hs,
    const float* __restrict__ dinv, const float* __restrict__ b,
    ushort_t* __restrict__ tmpb, int ts,
    int N, int M, int Q, ull_t magic, uint_t sh)
{
    const uint_t g = blockIdx.x * 256 + threadIdx.x;
    const uint_t i = (uint_t)(((ull_t)g * magic) >> sh);
    const int jp = (int)(g - i * Q);
    if (i >= (uint_t)N) return;
    const int j0 = jp * 4;
    if (j0 >= M) {
        *(uint2*)(tmpb + (long)i * ts + j0) = make_uint2(0u, 0u);
        return;
    }
    const int s0 = row_start[i];
    const int s1 = row_start[i + 1];
    const ushort_t* hp = h2 + j0;
    uint2 v = *(const uint2*)(hp + (long)i * hs);
    float a0 = bf2f((ushort_t)(v.x & 0xffff)), a1 = bf2f((ushort_t)(v.x >> 16));
    float a2 = bf2f((ushort_t)(v.y & 0xffff)), a3 = bf2f((ushort_t)(v.y >> 16));
    int e = s0;
    for (; e + 3 < s1; e += 4) {
        int n0 = csr_src[e], n1 = csr_src[e + 1], n2 = csr_src[e + 2], n3 = csr_src[e + 3];
        uint2 w0 = *(const uint2*)(hp + (long)n0 * hs);
        uint2 w1 = *(const uint2*)(hp + (long)n1 * hs);
        uint2 w2 = *(const uint2*)(hp + (long)n2 * hs);
        uint2 w3 = *(const uint2*)(hp + (long)n3 * hs);
        a0 += bf2f((ushort_t)(w0.x & 0xffff)); a1 += bf2f((ushort_t)(w0.x >> 16));
        a2 += bf2f((ushort_t)(w0.y & 0xffff)); a3 += bf2f((ushort_t)(w0.y >> 16));
        a0 += bf2f((ushort_t)(w1.x & 0xffff)); a1 += bf2f((ushort_t)(w1.x >> 16));
        a2 += bf2f((ushort_t)(w1.y & 0xffff)); a3 += bf2f((ushort_t)(w1.y >> 16));
        a0 += bf2f((ushort_t)(w2.x & 0xffff)); a1 += bf2f((ushort_t)(w2.x >> 16));
        a2 += bf2f((ushort_t)(w2.y & 0xffff)); a3 += bf2f((ushort_t)(w2.y >> 16));
        a0 += bf2f((ushort_t)(w3.x & 0xffff)); a1 += bf2f((ushort_t)(w3.x >> 16));
        a2 += bf2f((ushort_t)(w3.y & 0xffff)); a3 += bf2f((ushort_t)(w3.y >> 16));
    }
    for (; e < s1; ++e) {
        uint2 w = *(const uint2*)(hp + (long)csr_src[e] * hs);
        a0 += bf2f((ushort_t)(w.x & 0xffff)); a1 += bf2f((ushort_t)(w.x >> 16));
        a2 += bf2f((ushort_t)(w.y & 0xffff)); a3 += bf2f((ushort_t)(w.y >> 16));
    }
    const float di = dinv[i];
    float r0 = (j0     < M) ? fmaxf(a0 * di + b[j0],     0.f) : 0.f;
    float r1 = (j0 + 1 < M) ? fmaxf(a1 * di + b[j0 + 1], 0.f) : 0.f;
    float r2 = (j0 + 2 < M) ? fmaxf(a2 * di + b[j0 + 2], 0.f) : 0.f;
    float r3 = (j0 + 3 < M) ? fmaxf(a3 * di + b[j0 + 3], 0.f) : 0.f;
    uint2 pk;
    pk.x = (uint_t)f2bf(r0) | ((uint_t)f2bf(r1) << 16);
    pk.y = (uint_t)f2bf(r2) | ((uint_t)f2bf(r3) << 16);
    *(uint2*)(tmpb + (long)i * ts + j0) = pk;
}

// ---------------- BN stats (R6, unchanged) ----------------
__global__ __launch_bounds__(256) void k_stats(
    const ushort_t* __restrict__ tmpb, int ts,
    float* __restrict__ cs, float* __restrict__ csq, int N)
{
    const int t = threadIdx.x;
    if (2 * t >= ts) return;
    const int i0 = blockIdx.x * 64;
    float s0 = 0.f, q0 = 0.f, s1 = 0.f, q1 = 0.f;
    for (int r = 0; r < 64; ++r) {
        int i = i0 + r;
        if (i < N) {
            uint_t w = *(const uint_t*)(tmpb + (long)i * ts + 2 * t);
            float v0 = bf2f((ushort_t)(w & 0xffff));
            float v1 = bf2f((ushort_t)(w >> 16));
            s0 += v0; q0 += v0 * v0;
            s1 += v1; q1 += v1 * v1;
        }
    }
    atomicAdd(&cs[2 * t], s0);
    atomicAdd(&csq[2 * t], q0);
    atomicAdd(&cs[2 * t + 1], s1);
    atomicAdd(&csq[2 * t + 1], q1);
}

// ---------------- final layer: gather + bias + log_softmax ----------------
__global__ __launch_bounds__(256) void k_agg_final(
    const int* __restrict__ row_start, const int* __restrict__ csr_src,
    const ushort_t* __restrict__ h2, const float* __restrict__ dinv,
    const float* __restrict__ b, float* __restrict__ out, int N, int M)
{
    const int x = threadIdx.x;                 // 0..15
    const int i = blockIdx.x * 16 + threadIdx.y;
    if (i >= N) return;
    const int j0 = 2 * x, j1 = 2 * x + 1;
    uint_t v = *(const uint_t*)(h2 + (long)i * 32 + j0);
    float a0 = bf2f((ushort_t)(v & 0xffff));
    float a1 = bf2f((ushort_t)(v >> 16));
    const int s0 = row_start[i];
    const int s1 = row_start[i + 1];
    int e = s0;
    for (; e + 1 < s1; e += 2) {
        int n0 = csr_src[e], n1 = csr_src[e + 1];
        uint_t w0 = *(const uint_t*)(h2 + (long)n0 * 32 + j0);
        uint_t w1 = *(const uint_t*)(h2 + (long)n1 * 32 + j0);
        a0 += bf2f((ushort_t)(w0 & 0xffff)); a1 += bf2f((ushort_t)(w0 >> 16));
        a0 += bf2f((ushort_t)(w1 & 0xffff)); a1 += bf2f((ushort_t)(w1 >> 16));
    }
    for (; e < s1; ++e) {
        uint_t w = *(const uint_t*)(h2 + (long)csr_src[e] * 32 + j0);
        a0 += bf2f((ushort_t)(w & 0xffff)); a1 += bf2f((ushort_t)(w >> 16));
    }
    const float di = dinv[i];
    float r0 = (j0 < M) ? (a0 * di + b[j0]) : -INFINITY;
    float r1 = (j1 < M) ? (a1 * di + b[j1]) : -INFINITY;
    float m = fmaxf(r0, r1);
    #pragma unroll
    for (int msk = 1; msk < 16; msk <<= 1) m = fmaxf(m, __shfl_xor(m, msk, 16));
    float s = ((j0 < M) ? expf(r0 - m) : 0.f) + ((j1 < M) ? expf(r1 - m) : 0.f);
    #pragma unroll
    for (int msk = 1; msk < 16; msk <<= 1) s += __shfl_xor(s, msk, 16);
    const float l = logf(s) + m;
    if (j0 < M) out[(long)i * M + j0] = r0 - l;
    if (j1 < M) out[(long)i * M + j1] = r1 - l;
}

// ---------------- launch ----------------

static inline int pad16(int v) { return (v + 15) & ~15; }
static inline int pad32(int v) { return (v + 31) & ~31; }

extern "C" void kernel_launch(void* const* d_in, const int* in_sizes, int n_in,
                              void* d_out, int out_size, void* d_ws, size_t ws_size,
                              hipStream_t stream)
{
    const int dims[6] = {256, 220, 150, 100, 60, 17};
    const int N = in_sizes[0] / dims[0];      // 10000
    const int E = in_sizes[1] / 2;            // 320000

    const float* x  = (const float*)d_in[0];
    const int* ei   = (const int*)d_in[1];
    const int* srcv = ei;
    const int* dstv = ei + E;
    const float* Wl[5], *bl[5];
    for (int l = 0; l < 5; ++l) {
        Wl[l] = (const float*)d_in[2 + 2 * l];
        bl[l] = (const float*)d_in[3 + 2 * l];
    }
    const float* gl[4], *bel[4];
    for (int l = 0; l < 4; ++l) {
        gl[l]  = (const float*)d_in[12 + 2 * l];
        bel[l] = (const float*)d_in[13 + 2 * l];
    }
    float* out = (float*)d_out;

    // ---- workspace layout ----
    char* w = (char*)d_ws;
    const long NB  = ((long)N * 4 + 255) & ~255L;
    const long NB1 = ((long)(N + 1) * 4 + 255) & ~255L;
    const long EB  = ((long)E * 4 + 255) & ~255L;
    const long XBB = ((long)N * 256 * 2 + 255) & ~255L;
    const long FBB = ((long)N * 224 * 2 + 255) & ~255L;
    const long WTB = ((long)224 * 256 * 2 + 255) & ~255L;

    long o = 0;
    float* dinv      = (float*)(w + o);  o += NB;
    float* stats     = (float*)(w + o);  o += 2048 * 4;   // 4 layers x (cs[256]+cq[256])
    float* wbias     = (float*)(w + o);  o += 1024;
    int*   cnt       = (int*)(w + o);    o += NB;
    int*   row_start = (int*)(w + o);    o += NB1;
    int*   cursor    = (int*)(w + o);    o += NB;
    int*   csr_src   = (int*)(w + o);    o += EB;
    ushort_t* xb     = (ushort_t*)(w + o); o += XBB;
    ushort_t* Wt     = (ushort_t*)(w + o); o += WTB;
    ushort_t* h2     = (ushort_t*)(w + o); o += FBB;
    ushort_t* tmpb   = (ushort_t*)(w + o); o += FBB;

    const int eBlk = (E + 255) / 256;
    const float invN = 1.0f / (float)N;

    k_init<<<(N * 64 + 255) / 256, 256, 0, stream>>>(x, Wl[0], cnt, stats,
                                                     wbias, xb, Wt, N);
    k_hist<<<eBlk, 256, 0, stream>>>(dstv, cnt, E);
    k_scan<<<1, 1024, 0, stream>>>(cnt, row_start, cursor, dinv, N);
    k_fill<<<eBlk, 256, 0, stream>>>(srcv, dstv, cursor, csr_src, E);

    for (int l = 0; l < 5; ++l) {
        const int K  = dims[l];
        const int M  = dims[l + 1];
        const int Kp = pad32(K);
        const int Mp = pad16(M);
        const int ts = (l < 4) ? pad32(M) : 32;
        const ushort_t* X = (l == 0) ? xb : tmpb;

        if (l > 0) {
            const int yW = (Mp + 3) / 4;
            k_prep<<<dim3((Kp + 63) / 64, yW + 1), dim3(64, 4), 0, stream>>>(
                Wl[l], gl[l - 1], bel[l - 1],
                stats + (l - 1) * 512, stats + (l - 1) * 512 + 256,
                Wt, wbias, K, M, Kp, Mp, yW, invN);
        }

        dim3 gg((N + 15) / 16, (Mp + 63) / 64);
        switch (Kp) {
            case 256: k_gemm_mfma<256><<<gg, 64, 0, stream>>>(X, Wt, wbias, dinv, h2, N, Mp); break;
            case 224: k_gemm_mfma<224><<<gg, 64, 0, stream>>>(X, Wt, wbias, dinv, h2, N, Mp); break;
            case 160: k_gemm_mfma<160><<<gg, 64, 0, stream>>>(X, Wt, wbias, dinv, h2, N, Mp); break;
            case 128: k_gemm_mfma<128><<<gg, 64, 0, stream>>>(X, Wt, wbias, dinv, h2, N, Mp); break;
            case  64: k_gemm_mfma< 64><<<gg, 64, 0, stream>>>(X, Wt, wbias, dinv, h2, N, Mp); break;
        }

        if (l < 4) {
            const int Q = ts / 4;
            uint_t shmt = 0;
            while ((1u << shmt) < (uint_t)Q) ++shmt;
            shmt += 32;
            const ull_t magic = ((1ULL << shmt) + Q - 1) / (ull_t)Q;   // 64-bit (pow2 Q!)
            const long total = (long)N * Q;
            k_agg<<<(int)((total + 255) / 256), 256, 0, stream>>>(
                row_start, csr_src, h2, Mp, dinv, bl[l], tmpb, ts, N, M, Q, magic, shmt);
            k_stats<<<(N + 63) / 64, 256, 0, stream>>>(tmpb, ts,
                stats + l * 512, stats + l * 512 + 256, N);
        } else {
            k_agg_final<<<(N + 15) / 16, dim3(16, 16), 0, stream>>>(
                row_start, csr_src, h2, dinv, bl[l], out, N, M);
        }
    }
}

// Round 10
// 406.919 us; speedup vs baseline: 4.3187x; 1.0147x over previous
//
#include <hip/hip_runtime.h>
#include <math.h>

typedef unsigned short ushort_t;
typedef unsigned int uint_t;
typedef unsigned long long ull_t;

__device__ __forceinline__ float bf2f(ushort_t u) {
    union { uint_t i; float f; } x; x.i = ((uint_t)u) << 16; return x.f;
}
__device__ __forceinline__ ushort_t f2bf(float f) {
    union { float f; uint_t i; } x; x.f = f;
    uint_t r = x.i + 0x7FFFu + ((x.i >> 16) & 1u);
    return (ushort_t)(r >> 16);
}

// ---------------- init: zero cnt/stats + cvtx + prep layer 0 ----------------
__global__ __launch_bounds__(256) void k_init(
    const float* __restrict__ x, const float* __restrict__ W0,
    int* __restrict__ cnt, float* __restrict__ stats,
    float* __restrict__ wbias, ushort_t* __restrict__ xb, ushort_t* __restrict__ Wt,
    int N)
{
    const int gt = blockIdx.x * 256 + threadIdx.x;
    const int gth = gridDim.x * 256;
    for (int i = gt; i < N; i += gth) cnt[i] = 0;
    for (int i = gt; i < 2048; i += gth) stats[i] = 0.f;
    if (gt < 256) wbias[gt] = 0.f;          // layer-0 wbias = 0
    const int n4 = N * 64;
    for (int i = gt; i < n4; i += gth) {
        float4 v = ((const float4*)x)[i];
        ushort_t* o = xb + i * 4;
        o[0] = f2bf(v.x); o[1] = f2bf(v.y); o[2] = f2bf(v.z); o[3] = f2bf(v.w);
    }
    // prep0: Wt[j][k] = bf16(W0[k][j]); Kp=256, Mp=224, K=256, M=220
    for (int idx = gt; idx < 224 * 256; idx += gth) {
        int j = idx >> 8;
        int k = idx & 255;
        float v = (j < 220) ? W0[(long)k * 220 + j] : 0.f;
        Wt[idx] = f2bf(v);
    }
}

__global__ void k_hist(const int* __restrict__ dst, int* __restrict__ cnt, int E) {
    int e = blockIdx.x * blockDim.x + threadIdx.x;
    if (e < E) atomicAdd(&cnt[dst[e]], 1);
}

__global__ __launch_bounds__(1024) void k_scan(
    const int* __restrict__ cnt, int* __restrict__ row_start,
    int* __restrict__ cursor, float* __restrict__ dinv, int N)
{
    __shared__ int sh[1024];
    const int tid = threadIdx.x;
    const int chunk = (N + 1023) >> 10;
    int loc[16];
    const int base = tid * chunk;
    int sum = 0;
    for (int c = 0; c < chunk; ++c) {
        int i = base + c;
        int v = (i < N) ? cnt[i] : 0;
        loc[c] = sum;
        sum += v;
    }
    sh[tid] = sum;
    __syncthreads();
    for (int off = 1; off < 1024; off <<= 1) {
        int v = (tid >= off) ? sh[tid - off] : 0;
        __syncthreads();
        sh[tid] += v;
        __syncthreads();
    }
    const int excl = sh[tid] - sum;
    for (int c = 0; c < chunk; ++c) {
        int i = base + c;
        if (i < N) {
            int rs = excl + loc[c];
            row_start[i] = rs;
            cursor[i] = rs;
            dinv[i] = rsqrtf(1.0f + (float)cnt[i]);
        }
    }
    if (tid == 1023) row_start[N] = sh[1023];
}

__global__ void k_fill(const int* __restrict__ src, const int* __restrict__ dst,
                       int* __restrict__ cursor, int* __restrict__ csr_src, int E) {
    int e = blockIdx.x * blockDim.x + threadIdx.x;
    if (e < E) {
        int pos = atomicAdd(&cursor[dst[e]], 1);
        csr_src[pos] = src[e];
    }
}

// ---------------- fused prep: BN finalize (from stats) + Wt fold + wbias ----------------
__global__ void k_prep(const float* __restrict__ W,
                       const float* __restrict__ g, const float* __restrict__ be,
                       const float* __restrict__ cs, const float* __restrict__ cq,
                       ushort_t* __restrict__ Wt, float* __restrict__ wbias,
                       int K, int M, int Kp, int Mp, int yW, float invN)
{
    __shared__ float sm[256];
    if ((int)blockIdx.y < yW) {
        if (threadIdx.y == 0) {
            int kk = blockIdx.x * 64 + threadIdx.x;
            float sc = 0.f;
            if (kk < K) {
                float mu = cs[kk] * invN;
                float var = cq[kk] * invN - mu * mu;
                sc = g[kk] * rsqrtf(var + 1e-5f);
            }
            sm[threadIdx.x] = sc;
        }
        __syncthreads();
        int k = blockIdx.x * 64 + threadIdx.x;
        int j = blockIdx.y * 4 + threadIdx.y;
        if (k >= Kp || j >= Mp) return;
        float v = 0.f;
        if (k < K && j < M) v = sm[threadIdx.x] * W[(long)k * M + j];
        Wt[(long)j * Kp + k] = f2bf(v);
    } else {
        __shared__ float red[4][64];
        int t = threadIdx.y * 64 + threadIdx.x;
        for (int kk = t; kk < K; kk += 256) {
            float mu = cs[kk] * invN;
            float var = cq[kk] * invN - mu * mu;
            float sc = g[kk] * rsqrtf(var + 1e-5f);
            sm[kk] = be[kk] - mu * sc;
        }
        __syncthreads();
        int jl = t & 63, kg = t >> 6;
        int j = blockIdx.x * 64 + jl;
        float s = 0.f;
        if (j < M) {
            for (int k = kg; k < K; k += 4) s += sm[k] * W[(long)k * M + j];
        }
        red[kg][jl] = s;
        __syncthreads();
        if (kg == 0 && j < Mp) wbias[j] = red[0][jl] + red[1][jl] + red[2][jl] + red[3][jl];
    }
}

// ---------------- MFMA GEMM: 256 threads, 64x64 tile, LDS-staged B ----------------
// B panel (64 cols x Kp) staged once, reused by 4 waves x all k0. Stride Kp+16
// shorts -> max 2-way LDS bank aliasing (free).
template<int KP>
__global__ __launch_bounds__(256) void k_gemm_mfma(
    const ushort_t* __restrict__ Xb, const ushort_t* __restrict__ Wt,
    const float* __restrict__ wbias, const float* __restrict__ dinv,
    ushort_t* __restrict__ h2, int N, int Mp)
{
    typedef __attribute__((ext_vector_type(8))) short short8;
    typedef __attribute__((ext_vector_type(4))) float floatx4;
    constexpr int LSTR = KP + 16;               // shorts
    __shared__ ushort_t Bs[64 * LSTR];          // <= 34.8 KB @ KP=256

    const int tid = threadIdx.x;
    const int wave = tid >> 6, lane = tid & 63;
    const int m = lane & 15, quad = lane >> 4;
    const int i0 = blockIdx.x * 64 + wave * 16;
    const int j0 = blockIdx.y * 64;
    const int ncols = min(64, Mp - j0);
    const int ntiles = ncols >> 4;

    // stage B panel: ncols rows of Wt (KP shorts each), short8 chunks
    {
        const int cpr = KP / 8;                 // chunks per row
        const int chunks = ncols * cpr;
        for (int c = tid; c < chunks; c += 256) {
            int jj = c / cpr;
            int kk = (c - jj * cpr) * 8;
            *(short8*)(Bs + jj * LSTR + kk) =
                *(const short8*)(Wt + (long)(j0 + jj) * KP + kk);
        }
    }
    __syncthreads();

    if (i0 >= N) return;                        // no barriers after this point

    floatx4 acc[4];
    #pragma unroll
    for (int t = 0; t < 4; ++t) { acc[t].x = 0.f; acc[t].y = 0.f; acc[t].z = 0.f; acc[t].w = 0.f; }

    const int ra = min(i0 + m, N - 1);
    const ushort_t* arow = Xb + (long)ra * KP + quad * 8;

    #pragma unroll
    for (int k0 = 0; k0 < KP; k0 += 32) {
        short8 av = *(const short8*)(arow + k0);
        #pragma unroll
        for (int t = 0; t < 4; ++t) {
            if (t < ntiles) {
                short8 bv = *(const short8*)(Bs + (t * 16 + m) * LSTR + k0 + quad * 8);
                acc[t] = __builtin_amdgcn_mfma_f32_16x16x32_bf16(av, bv, acc[t], 0, 0, 0);
            }
        }
    }

    #pragma unroll
    for (int t = 0; t < 4; ++t) {
        if (t < ntiles) {
            int j = j0 + t * 16 + m;
            float wb = wbias[j];
            #pragma unroll
            for (int r = 0; r < 4; ++r) {
                int i = i0 + quad * 4 + r;
                if (i < N) h2[(long)i * Mp + j] = f2bf((acc[t][r] + wb) * dinv[i]);
            }
        }
    }
}

// ---------------- aggregation (R9, unchanged; 64-bit magic) ----------------
__global__ __launch_bounds__(256) void k_agg(
    const int* __restrict__ row_start, const int* __restrict__ csr_src,
    const ushort_t* __restrict__ h2, int hs,
    const float* __restrict__ dinv, const float* __restrict__ b,
    ushort_t* __restrict__ tmpb, int ts,
    int N, int M, int Q, ull_t magic, uint_t sh)
{
    const uint_t g = blockIdx.x * 256 + threadIdx.x;
    const uint_t i = (uint_t)(((ull_t)g * magic) >> sh);
    const int jp = (int)(g - i * Q);
    if (i >= (uint_t)N) return;
    const int j0 = jp * 4;
    if (j0 >= M) {
        *(uint2*)(tmpb + (long)i * ts + j0) = make_uint2(0u, 0u);
        return;
    }
    const int s0 = row_start[i];
    const int s1 = row_start[i + 1];
    const ushort_t* hp = h2 + j0;
    uint2 v = *(const uint2*)(hp + (long)i * hs);
    float a0 = bf2f((ushort_t)(v.x & 0xffff)), a1 = bf2f((ushort_t)(v.x >> 16));
    float a2 = bf2f((ushort_t)(v.y & 0xffff)), a3 = bf2f((ushort_t)(v.y >> 16));
    int e = s0;
    for (; e + 3 < s1; e += 4) {
        int n0 = csr_src[e], n1 = csr_src[e + 1], n2 = csr_src[e + 2], n3 = csr_src[e + 3];
        uint2 w0 = *(const uint2*)(hp + (long)n0 * hs);
        uint2 w1 = *(const uint2*)(hp + (long)n1 * hs);
        uint2 w2 = *(const uint2*)(hp + (long)n2 * hs);
        uint2 w3 = *(const uint2*)(hp + (long)n3 * hs);
        a0 += bf2f((ushort_t)(w0.x & 0xffff)); a1 += bf2f((ushort_t)(w0.x >> 16));
        a2 += bf2f((ushort_t)(w0.y & 0xffff)); a3 += bf2f((ushort_t)(w0.y >> 16));
        a0 += bf2f((ushort_t)(w1.x & 0xffff)); a1 += bf2f((ushort_t)(w1.x >> 16));
        a2 += bf2f((ushort_t)(w1.y & 0xffff)); a3 += bf2f((ushort_t)(w1.y >> 16));
        a0 += bf2f((ushort_t)(w2.x & 0xffff)); a1 += bf2f((ushort_t)(w2.x >> 16));
        a2 += bf2f((ushort_t)(w2.y & 0xffff)); a3 += bf2f((ushort_t)(w2.y >> 16));
        a0 += bf2f((ushort_t)(w3.x & 0xffff)); a1 += bf2f((ushort_t)(w3.x >> 16));
        a2 += bf2f((ushort_t)(w3.y & 0xffff)); a3 += bf2f((ushort_t)(w3.y >> 16));
    }
    for (; e < s1; ++e) {
        uint2 w = *(const uint2*)(hp + (long)csr_src[e] * hs);
        a0 += bf2f((ushort_t)(w.x & 0xffff)); a1 += bf2f((ushort_t)(w.x >> 16));
        a2 += bf2f((ushort_t)(w.y & 0xffff)); a3 += bf2f((ushort_t)(w.y >> 16));
    }
    const float di = dinv[i];
    float r0 = (j0     < M) ? fmaxf(a0 * di + b[j0],     0.f) : 0.f;
    float r1 = (j0 + 1 < M) ? fmaxf(a1 * di + b[j0 + 1], 0.f) : 0.f;
    float r2 = (j0 + 2 < M) ? fmaxf(a2 * di + b[j0 + 2], 0.f) : 0.f;
    float r3 = (j0 + 3 < M) ? fmaxf(a3 * di + b[j0 + 3], 0.f) : 0.f;
    uint2 pk;
    pk.x = (uint_t)f2bf(r0) | ((uint_t)f2bf(r1) << 16);
    pk.y = (uint_t)f2bf(r2) | ((uint_t)f2bf(r3) << 16);
    *(uint2*)(tmpb + (long)i * ts + j0) = pk;
}

// ---------------- BN stats (R9, unchanged) ----------------
__global__ __launch_bounds__(256) void k_stats(
    const ushort_t* __restrict__ tmpb, int ts,
    float* __restrict__ cs, float* __restrict__ csq, int N)
{
    const int t = threadIdx.x;
    if (2 * t >= ts) return;
    const int i0 = blockIdx.x * 64;
    float s0 = 0.f, q0 = 0.f, s1 = 0.f, q1 = 0.f;
    for (int r = 0; r < 64; ++r) {
        int i = i0 + r;
        if (i < N) {
            uint_t w = *(const uint_t*)(tmpb + (long)i * ts + 2 * t);
            float v0 = bf2f((ushort_t)(w & 0xffff));
            float v1 = bf2f((ushort_t)(w >> 16));
            s0 += v0; q0 += v0 * v0;
            s1 += v1; q1 += v1 * v1;
        }
    }
    atomicAdd(&cs[2 * t], s0);
    atomicAdd(&csq[2 * t], q0);
    atomicAdd(&cs[2 * t + 1], s1);
    atomicAdd(&csq[2 * t + 1], q1);
}

// ---------------- final layer: gather + bias + log_softmax ----------------
__global__ __launch_bounds__(256) void k_agg_final(
    const int* __restrict__ row_start, const int* __restrict__ csr_src,
    const ushort_t* __restrict__ h2, const float* __restrict__ dinv,
    const float* __restrict__ b, float* __restrict__ out, int N, int M)
{
    const int x = threadIdx.x;                 // 0..15
    const int i = blockIdx.x * 16 + threadIdx.y;
    if (i >= N) return;
    const int j0 = 2 * x, j1 = 2 * x + 1;
    uint_t v = *(const uint_t*)(h2 + (long)i * 32 + j0);
    float a0 = bf2f((ushort_t)(v & 0xffff));
    float a1 = bf2f((ushort_t)(v >> 16));
    const int s0 = row_start[i];
    const int s1 = row_start[i + 1];
    int e = s0;
    for (; e + 1 < s1; e += 2) {
        int n0 = csr_src[e], n1 = csr_src[e + 1];
        uint_t w0 = *(const uint_t*)(h2 + (long)n0 * 32 + j0);
        uint_t w1 = *(const uint_t*)(h2 + (long)n1 * 32 + j0);
        a0 += bf2f((ushort_t)(w0 & 0xffff)); a1 += bf2f((ushort_t)(w0 >> 16));
        a0 += bf2f((ushort_t)(w1 & 0xffff)); a1 += bf2f((ushort_t)(w1 >> 16));
    }
    for (; e < s1; ++e) {
        uint_t w = *(const uint_t*)(h2 + (long)csr_src[e] * 32 + j0);
        a0 += bf2f((ushort_t)(w & 0xffff)); a1 += bf2f((ushort_t)(w >> 16));
    }
    const float di = dinv[i];
    float r0 = (j0 < M) ? (a0 * di + b[j0]) : -INFINITY;
    float r1 = (j1 < M) ? (a1 * di + b[j1]) : -INFINITY;
    float m = fmaxf(r0, r1);
    #pragma unroll
    for (int msk = 1; msk < 16; msk <<= 1) m = fmaxf(m, __shfl_xor(m, msk, 16));
    float s = ((j0 < M) ? expf(r0 - m) : 0.f) + ((j1 < M) ? expf(r1 - m) : 0.f);
    #pragma unroll
    for (int msk = 1; msk < 16; msk <<= 1) s += __shfl_xor(s, msk, 16);
    const float l = logf(s) + m;
    if (j0 < M) out[(long)i * M + j0] = r0 - l;
    if (j1 < M) out[(long)i * M + j1] = r1 - l;
}

// ---------------- launch ----------------

static inline int pad16(int v) { return (v + 15) & ~15; }
static inline int pad32(int v) { return (v + 31) & ~31; }

extern "C" void kernel_launch(void* const* d_in, const int* in_sizes, int n_in,
                              void* d_out, int out_size, void* d_ws, size_t ws_size,
                              hipStream_t stream)
{
    const int dims[6] = {256, 220, 150, 100, 60, 17};
    const int N = in_sizes[0] / dims[0];      // 10000
    const int E = in_sizes[1] / 2;            // 320000

    const float* x  = (const float*)d_in[0];
    const int* ei   = (const int*)d_in[1];
    const int* srcv = ei;
    const int* dstv = ei + E;
    const float* Wl[5], *bl[5];
    for (int l = 0; l < 5; ++l) {
        Wl[l] = (const float*)d_in[2 + 2 * l];
        bl[l] = (const float*)d_in[3 + 2 * l];
    }
    const float* gl[4], *bel[4];
    for (int l = 0; l < 4; ++l) {
        gl[l]  = (const float*)d_in[12 + 2 * l];
        bel[l] = (const float*)d_in[13 + 2 * l];
    }
    float* out = (float*)d_out;

    // ---- workspace layout ----
    char* w = (char*)d_ws;
    const long NB  = ((long)N * 4 + 255) & ~255L;
    const long NB1 = ((long)(N + 1) * 4 + 255) & ~255L;
    const long EB  = ((long)E * 4 + 255) & ~255L;
    const long XBB = ((long)N * 256 * 2 + 255) & ~255L;
    const long FBB = ((long)N * 224 * 2 + 255) & ~255L;
    const long WTB = ((long)224 * 256 * 2 + 255) & ~255L;

    long o = 0;
    float* dinv      = (float*)(w + o);  o += NB;
    float* stats     = (float*)(w + o);  o += 2048 * 4;   // 4 layers x (cs[256]+cq[256])
    float* wbias     = (float*)(w + o);  o += 1024;
    int*   cnt       = (int*)(w + o);    o += NB;
    int*   row_start = (int*)(w + o);    o += NB1;
    int*   cursor    = (int*)(w + o);    o += NB;
    int*   csr_src   = (int*)(w + o);    o += EB;
    ushort_t* xb     = (ushort_t*)(w + o); o += XBB;
    ushort_t* Wt     = (ushort_t*)(w + o); o += WTB;
    ushort_t* h2     = (ushort_t*)(w + o); o += FBB;
    ushort_t* tmpb   = (ushort_t*)(w + o); o += FBB;

    const int eBlk = (E + 255) / 256;
    const float invN = 1.0f / (float)N;

    k_init<<<(N * 64 + 255) / 256, 256, 0, stream>>>(x, Wl[0], cnt, stats,
                                                     wbias, xb, Wt, N);
    k_hist<<<eBlk, 256, 0, stream>>>(dstv, cnt, E);
    k_scan<<<1, 1024, 0, stream>>>(cnt, row_start, cursor, dinv, N);
    k_fill<<<eBlk, 256, 0, stream>>>(srcv, dstv, cursor, csr_src, E);

    for (int l = 0; l < 5; ++l) {
        const int K  = dims[l];
        const int M  = dims[l + 1];
        const int Kp = pad32(K);
        const int Mp = pad16(M);
        const int ts = (l < 4) ? pad32(M) : 32;
        const ushort_t* X = (l == 0) ? xb : tmpb;

        if (l > 0) {
            const int yW = (Mp + 3) / 4;
            k_prep<<<dim3((Kp + 63) / 64, yW + 1), dim3(64, 4), 0, stream>>>(
                Wl[l], gl[l - 1], bel[l - 1],
                stats + (l - 1) * 512, stats + (l - 1) * 512 + 256,
                Wt, wbias, K, M, Kp, Mp, yW, invN);
        }

        dim3 gg((N + 63) / 64, (Mp + 63) / 64);
        switch (Kp) {
            case 256: k_gemm_mfma<256><<<gg, 256, 0, stream>>>(X, Wt, wbias, dinv, h2, N, Mp); break;
            case 224: k_gemm_mfma<224><<<gg, 256, 0, stream>>>(X, Wt, wbias, dinv, h2, N, Mp); break;
            case 160: k_gemm_mfma<160><<<gg, 256, 0, stream>>>(X, Wt, wbias, dinv, h2, N, Mp); break;
            case 128: k_gemm_mfma<128><<<gg, 256, 0, stream>>>(X, Wt, wbias, dinv, h2, N, Mp); break;
            case  64: k_gemm_mfma< 64><<<gg, 256, 0, stream>>>(X, Wt, wbias, dinv, h2, N, Mp); break;
        }

        if (l < 4) {
            const int Q = ts / 4;
            uint_t shmt = 0;
            while ((1u << shmt) < (uint_t)Q) ++shmt;
            shmt += 32;
            const ull_t magic = ((1ULL << shmt) + Q - 1) / (ull_t)Q;   // 64-bit (pow2 Q!)
            const long total = (long)N * Q;
            k_agg<<<(int)((total + 255) / 256), 256, 0, stream>>>(
                row_start, csr_src, h2, Mp, dinv, bl[l], tmpb, ts, N, M, Q, magic, shmt);
            k_stats<<<(N + 63) / 64, 256, 0, stream>>>(tmpb, ts,
                stats + l * 512, stats + l * 512 + 256, N);
        } else {
            k_agg_final<<<(N + 15) / 16, dim3(16, 16), 0, stream>>>(
                row_start, csr_src, h2, dinv, bl[l], out, N, M);
        }
    }
}

// Round 11
// 400.629 us; speedup vs baseline: 4.3865x; 1.0157x over previous
//
#include <hip/hip_runtime.h>
#include <math.h>

typedef unsigned short ushort_t;
typedef unsigned int uint_t;
typedef unsigned long long ull_t;

__device__ __forceinline__ float bf2f(ushort_t u) {
    union { uint_t i; float f; } x; x.i = ((uint_t)u) << 16; return x.f;
}
__device__ __forceinline__ ushort_t f2bf(float f) {
    union { float f; uint_t i; } x; x.f = f;
    uint_t r = x.i + 0x7FFFu + ((x.i >> 16) & 1u);
    return (ushort_t)(r >> 16);
}

// ---------------- init: zero cnt/stats/wbias only ----------------
__global__ __launch_bounds__(256) void k_init(
    int* __restrict__ cnt, float* __restrict__ stats, float* __restrict__ wbias, int N)
{
    const int gt = blockIdx.x * 256 + threadIdx.x;
    const int gth = gridDim.x * 256;
    for (int i = gt; i < N; i += gth) cnt[i] = 0;
    for (int i = gt; i < 2048; i += gth) stats[i] = 0.f;
    if (gt < 256) wbias[gt] = 0.f;          // layer-0 wbias = 0
}

// prep0 separate (small): Wt[j][k] = bf16(W0[k][j]); K=256, M=220, Mp=224
__global__ __launch_bounds__(256) void k_prep0(
    const float* __restrict__ W0, ushort_t* __restrict__ Wt)
{
    const int gt = blockIdx.x * 256 + threadIdx.x;
    const int gth = gridDim.x * 256;
    for (int idx = gt; idx < 224 * 256; idx += gth) {
        int j = idx >> 8;
        int k = idx & 255;
        float v = (j < 220) ? W0[(long)k * 220 + j] : 0.f;
        Wt[idx] = f2bf(v);
    }
}

__global__ void k_hist(const int* __restrict__ dst, int* __restrict__ cnt, int E) {
    int e = blockIdx.x * blockDim.x + threadIdx.x;
    if (e < E) atomicAdd(&cnt[dst[e]], 1);
}

__global__ __launch_bounds__(1024) void k_scan(
    const int* __restrict__ cnt, int* __restrict__ row_start,
    int* __restrict__ cursor, float* __restrict__ dinv, int N)
{
    __shared__ int sh[1024];
    const int tid = threadIdx.x;
    const int chunk = (N + 1023) >> 10;
    int loc[16];
    const int base = tid * chunk;
    int sum = 0;
    for (int c = 0; c < chunk; ++c) {
        int i = base + c;
        int v = (i < N) ? cnt[i] : 0;
        loc[c] = sum;
        sum += v;
    }
    sh[tid] = sum;
    __syncthreads();
    for (int off = 1; off < 1024; off <<= 1) {
        int v = (tid >= off) ? sh[tid - off] : 0;
        __syncthreads();
        sh[tid] += v;
        __syncthreads();
    }
    const int excl = sh[tid] - sum;
    for (int c = 0; c < chunk; ++c) {
        int i = base + c;
        if (i < N) {
            int rs = excl + loc[c];
            row_start[i] = rs;
            cursor[i] = rs;
            dinv[i] = rsqrtf(1.0f + (float)cnt[i]);
        }
    }
    if (tid == 1023) row_start[N] = sh[1023];
}

__global__ void k_fill(const int* __restrict__ src, const int* __restrict__ dst,
                       int* __restrict__ cursor, int* __restrict__ csr_src, int E) {
    int e = blockIdx.x * blockDim.x + threadIdx.x;
    if (e < E) {
        int pos = atomicAdd(&cursor[dst[e]], 1);
        csr_src[pos] = src[e];
    }
}

// ---------------- fused prep: BN finalize (from stats) + Wt fold + wbias ----------------
__global__ void k_prep(const float* __restrict__ W,
                       const float* __restrict__ g, const float* __restrict__ be,
                       const float* __restrict__ cs, const float* __restrict__ cq,
                       ushort_t* __restrict__ Wt, float* __restrict__ wbias,
                       int K, int M, int Kp, int Mp, int yW, float invN)
{
    __shared__ float sm[256];
    if ((int)blockIdx.y < yW) {
        if (threadIdx.y == 0) {
            int kk = blockIdx.x * 64 + threadIdx.x;
            float sc = 0.f;
            if (kk < K) {
                float mu = cs[kk] * invN;
                float var = cq[kk] * invN - mu * mu;
                sc = g[kk] * rsqrtf(var + 1e-5f);
            }
            sm[threadIdx.x] = sc;
        }
        __syncthreads();
        int k = blockIdx.x * 64 + threadIdx.x;
        int j = blockIdx.y * 4 + threadIdx.y;
        if (k >= Kp || j >= Mp) return;
        float v = 0.f;
        if (k < K && j < M) v = sm[threadIdx.x] * W[(long)k * M + j];
        Wt[(long)j * Kp + k] = f2bf(v);
    } else {
        __shared__ float red[4][64];
        int t = threadIdx.y * 64 + threadIdx.x;
        for (int kk = t; kk < K; kk += 256) {
            float mu = cs[kk] * invN;
            float var = cq[kk] * invN - mu * mu;
            float sc = g[kk] * rsqrtf(var + 1e-5f);
            sm[kk] = be[kk] - mu * sc;
        }
        __syncthreads();
        int jl = t & 63, kg = t >> 6;
        int j = blockIdx.x * 64 + jl;
        float s = 0.f;
        if (j < M) {
            for (int k = kg; k < K; k += 4) s += sm[k] * W[(long)k * M + j];
        }
        red[kg][jl] = s;
        __syncthreads();
        if (kg == 0 && j < Mp) wbias[j] = red[0][jl] + red[1][jl] + red[2][jl] + red[3][jl];
    }
}

// ---------------- MFMA GEMM: 256 threads, 64x64 tile, LDS-staged B ----------------
// F32A: A operand is fp32 (layer 0's raw x), converted to bf16 in-register.
template<int KP, bool F32A>
__global__ __launch_bounds__(256) void k_gemm_mfma(
    const void* __restrict__ Xin, const ushort_t* __restrict__ Wt,
    const float* __restrict__ wbias, const float* __restrict__ dinv,
    ushort_t* __restrict__ h2, int N, int Mp)
{
    typedef __attribute__((ext_vector_type(8))) short short8;
    typedef __attribute__((ext_vector_type(4))) float floatx4;
    constexpr int LSTR = KP + 16;               // shorts
    __shared__ ushort_t Bs[64 * LSTR];          // <= 34.8 KB @ KP=256

    const int tid = threadIdx.x;
    const int wave = tid >> 6, lane = tid & 63;
    const int m = lane & 15, quad = lane >> 4;
    const int i0 = blockIdx.x * 64 + wave * 16;
    const int j0 = blockIdx.y * 64;
    const int ncols = min(64, Mp - j0);
    const int ntiles = ncols >> 4;

    // stage B panel
    {
        const int cpr = KP / 8;
        const int chunks = ncols * cpr;
        for (int c = tid; c < chunks; c += 256) {
            int jj = c / cpr;
            int kk = (c - jj * cpr) * 8;
            *(short8*)(Bs + jj * LSTR + kk) =
                *(const short8*)(Wt + (long)(j0 + jj) * KP + kk);
        }
    }
    __syncthreads();

    if (i0 >= N) return;

    floatx4 acc[4];
    #pragma unroll
    for (int t = 0; t < 4; ++t) { acc[t].x = 0.f; acc[t].y = 0.f; acc[t].z = 0.f; acc[t].w = 0.f; }

    const int ra = min(i0 + m, N - 1);
    const ushort_t* arow_h = F32A ? nullptr : (const ushort_t*)Xin + (long)ra * KP + quad * 8;
    const float*    arow_f = F32A ? (const float*)Xin + (long)ra * KP + quad * 8 : nullptr;

    #pragma unroll
    for (int k0 = 0; k0 < KP; k0 += 32) {
        short8 av;
        if (F32A) {
            float4 f0 = *(const float4*)(arow_f + k0);
            float4 f1 = *(const float4*)(arow_f + k0 + 4);
            av[0] = (short)f2bf(f0.x); av[1] = (short)f2bf(f0.y);
            av[2] = (short)f2bf(f0.z); av[3] = (short)f2bf(f0.w);
            av[4] = (short)f2bf(f1.x); av[5] = (short)f2bf(f1.y);
            av[6] = (short)f2bf(f1.z); av[7] = (short)f2bf(f1.w);
        } else {
            av = *(const short8*)(arow_h + k0);
        }
        #pragma unroll
        for (int t = 0; t < 4; ++t) {
            if (t < ntiles) {
                short8 bv = *(const short8*)(Bs + (t * 16 + m) * LSTR + k0 + quad * 8);
                acc[t] = __builtin_amdgcn_mfma_f32_16x16x32_bf16(av, bv, acc[t], 0, 0, 0);
            }
        }
    }

    #pragma unroll
    for (int t = 0; t < 4; ++t) {
        if (t < ntiles) {
            int j = j0 + t * 16 + m;
            float wb = wbias[j];
            #pragma unroll
            for (int r = 0; r < 4; ++r) {
                int i = i0 + quad * 4 + r;
                if (i < N) h2[(long)i * Mp + j] = f2bf((acc[t][r] + wb) * dinv[i]);
            }
        }
    }
}

// ---------------- aggregation (CSR gather, uint4 = 8 bf16/thread) ----------------
__global__ __launch_bounds__(256) void k_agg(
    const int* __restrict__ row_start, const int* __restrict__ csr_src,
    const ushort_t* __restrict__ h2, int hs,
    const float* __restrict__ dinv, const float* __restrict__ b,
    ushort_t* __restrict__ tmpb, int ts,
    int N, int M, int Q, ull_t magic, uint_t sh)
{
    const uint_t g = blockIdx.x * 256 + threadIdx.x;
    const uint_t i = (uint_t)(((ull_t)g * magic) >> sh);
    const int jp = (int)(g - i * Q);
    if (i >= (uint_t)N) return;
    const int j0 = jp * 8;
    if (j0 >= M) {
        *(uint4*)(tmpb + (long)i * ts + j0) = make_uint4(0u, 0u, 0u, 0u);
        return;
    }
    const int s0 = row_start[i];
    const int s1 = row_start[i + 1];
    const ushort_t* hp = h2 + j0;
    float acc[8];
    {
        uint4 v = *(const uint4*)(hp + (long)i * hs);
        acc[0] = bf2f((ushort_t)(v.x & 0xffff)); acc[1] = bf2f((ushort_t)(v.x >> 16));
        acc[2] = bf2f((ushort_t)(v.y & 0xffff)); acc[3] = bf2f((ushort_t)(v.y >> 16));
        acc[4] = bf2f((ushort_t)(v.z & 0xffff)); acc[5] = bf2f((ushort_t)(v.z >> 16));
        acc[6] = bf2f((ushort_t)(v.w & 0xffff)); acc[7] = bf2f((ushort_t)(v.w >> 16));
    }
    int e = s0;
    for (; e + 3 < s1; e += 4) {
        int n0 = csr_src[e], n1 = csr_src[e + 1], n2 = csr_src[e + 2], n3 = csr_src[e + 3];
        uint4 w0 = *(const uint4*)(hp + (long)n0 * hs);
        uint4 w1 = *(const uint4*)(hp + (long)n1 * hs);
        uint4 w2 = *(const uint4*)(hp + (long)n2 * hs);
        uint4 w3 = *(const uint4*)(hp + (long)n3 * hs);
        acc[0] += bf2f((ushort_t)(w0.x & 0xffff)); acc[1] += bf2f((ushort_t)(w0.x >> 16));
        acc[2] += bf2f((ushort_t)(w0.y & 0xffff)); acc[3] += bf2f((ushort_t)(w0.y >> 16));
        acc[4] += bf2f((ushort_t)(w0.z & 0xffff)); acc[5] += bf2f((ushort_t)(w0.z >> 16));
        acc[6] += bf2f((ushort_t)(w0.w & 0xffff)); acc[7] += bf2f((ushort_t)(w0.w >> 16));
        acc[0] += bf2f((ushort_t)(w1.x & 0xffff)); acc[1] += bf2f((ushort_t)(w1.x >> 16));
        acc[2] += bf2f((ushort_t)(w1.y & 0xffff)); acc[3] += bf2f((ushort_t)(w1.y >> 16));
        acc[4] += bf2f((ushort_t)(w1.z & 0xffff)); acc[5] += bf2f((ushort_t)(w1.z >> 16));
        acc[6] += bf2f((ushort_t)(w1.w & 0xffff)); acc[7] += bf2f((ushort_t)(w1.w >> 16));
        acc[0] += bf2f((ushort_t)(w2.x & 0xffff)); acc[1] += bf2f((ushort_t)(w2.x >> 16));
        acc[2] += bf2f((ushort_t)(w2.y & 0xffff)); acc[3] += bf2f((ushort_t)(w2.y >> 16));
        acc[4] += bf2f((ushort_t)(w2.z & 0xffff)); acc[5] += bf2f((ushort_t)(w2.z >> 16));
        acc[6] += bf2f((ushort_t)(w2.w & 0xffff)); acc[7] += bf2f((ushort_t)(w2.w >> 16));
        acc[0] += bf2f((ushort_t)(w3.x & 0xffff)); acc[1] += bf2f((ushort_t)(w3.x >> 16));
        acc[2] += bf2f((ushort_t)(w3.y & 0xffff)); acc[3] += bf2f((ushort_t)(w3.y >> 16));
        acc[4] += bf2f((ushort_t)(w3.z & 0xffff)); acc[5] += bf2f((ushort_t)(w3.z >> 16));
        acc[6] += bf2f((ushort_t)(w3.w & 0xffff)); acc[7] += bf2f((ushort_t)(w3.w >> 16));
    }
    for (; e < s1; ++e) {
        uint4 w = *(const uint4*)(hp + (long)csr_src[e] * hs);
        acc[0] += bf2f((ushort_t)(w.x & 0xffff)); acc[1] += bf2f((ushort_t)(w.x >> 16));
        acc[2] += bf2f((ushort_t)(w.y & 0xffff)); acc[3] += bf2f((ushort_t)(w.y >> 16));
        acc[4] += bf2f((ushort_t)(w.z & 0xffff)); acc[5] += bf2f((ushort_t)(w.z >> 16));
        acc[6] += bf2f((ushort_t)(w.w & 0xffff)); acc[7] += bf2f((ushort_t)(w.w >> 16));
    }
    const float di = dinv[i];
    ushort_t r[8];
    #pragma unroll
    for (int u = 0; u < 8; ++u) {
        float v = (j0 + u < M) ? fmaxf(acc[u] * di + b[j0 + u], 0.f) : 0.f;
        r[u] = f2bf(v);
    }
    uint4 pk;
    pk.x = (uint_t)r[0] | ((uint_t)r[1] << 16);
    pk.y = (uint_t)r[2] | ((uint_t)r[3] << 16);
    pk.z = (uint_t)r[4] | ((uint_t)r[5] << 16);
    pk.w = (uint_t)r[6] | ((uint_t)r[7] << 16);
    *(uint4*)(tmpb + (long)i * ts + j0) = pk;
}

// ---------------- BN stats (unchanged) ----------------
__global__ __launch_bounds__(256) void k_stats(
    const ushort_t* __restrict__ tmpb, int ts,
    float* __restrict__ cs, float* __restrict__ csq, int N)
{
    const int t = threadIdx.x;
    if (2 * t >= ts) return;
    const int i0 = blockIdx.x * 64;
    float s0 = 0.f, q0 = 0.f, s1 = 0.f, q1 = 0.f;
    for (int r = 0; r < 64; ++r) {
        int i = i0 + r;
        if (i < N) {
            uint_t w = *(const uint_t*)(tmpb + (long)i * ts + 2 * t);
            float v0 = bf2f((ushort_t)(w & 0xffff));
            float v1 = bf2f((ushort_t)(w >> 16));
            s0 += v0; q0 += v0 * v0;
            s1 += v1; q1 += v1 * v1;
        }
    }
    atomicAdd(&cs[2 * t], s0);
    atomicAdd(&csq[2 * t], q0);
    atomicAdd(&cs[2 * t + 1], s1);
    atomicAdd(&csq[2 * t + 1], q1);
}

// ---------------- final layer: gather + bias + log_softmax ----------------
__global__ __launch_bounds__(256) void k_agg_final(
    const int* __restrict__ row_start, const int* __restrict__ csr_src,
    const ushort_t* __restrict__ h2, const float* __restrict__ dinv,
    const float* __restrict__ b, float* __restrict__ out, int N, int M)
{
    const int x = threadIdx.x;                 // 0..15
    const int i = blockIdx.x * 16 + threadIdx.y;
    if (i >= N) return;
    const int j0 = 2 * x, j1 = 2 * x + 1;
    uint_t v = *(const uint_t*)(h2 + (long)i * 32 + j0);
    float a0 = bf2f((ushort_t)(v & 0xffff));
    float a1 = bf2f((ushort_t)(v >> 16));
    const int s0 = row_start[i];
    const int s1 = row_start[i + 1];
    int e = s0;
    for (; e + 1 < s1; e += 2) {
        int n0 = csr_src[e], n1 = csr_src[e + 1];
        uint_t w0 = *(const uint_t*)(h2 + (long)n0 * 32 + j0);
        uint_t w1 = *(const uint_t*)(h2 + (long)n1 * 32 + j0);
        a0 += bf2f((ushort_t)(w0 & 0xffff)); a1 += bf2f((ushort_t)(w0 >> 16));
        a0 += bf2f((ushort_t)(w1 & 0xffff)); a1 += bf2f((ushort_t)(w1 >> 16));
    }
    for (; e < s1; ++e) {
        uint_t w = *(const uint_t*)(h2 + (long)csr_src[e] * 32 + j0);
        a0 += bf2f((ushort_t)(w & 0xffff)); a1 += bf2f((ushort_t)(w >> 16));
    }
    const float di = dinv[i];
    float r0 = (j0 < M) ? (a0 * di + b[j0]) : -INFINITY;
    float r1 = (j1 < M) ? (a1 * di + b[j1]) : -INFINITY;
    float m = fmaxf(r0, r1);
    #pragma unroll
    for (int msk = 1; msk < 16; msk <<= 1) m = fmaxf(m, __shfl_xor(m, msk, 16));
    float s = ((j0 < M) ? expf(r0 - m) : 0.f) + ((j1 < M) ? expf(r1 - m) : 0.f);
    #pragma unroll
    for (int msk = 1; msk < 16; msk <<= 1) s += __shfl_xor(s, msk, 16);
    const float l = logf(s) + m;
    if (j0 < M) out[(long)i * M + j0] = r0 - l;
    if (j1 < M) out[(long)i * M + j1] = r1 - l;
}

// ---------------- launch ----------------

static inline int pad16(int v) { return (v + 15) & ~15; }
static inline int pad32(int v) { return (v + 31) & ~31; }

extern "C" void kernel_launch(void* const* d_in, const int* in_sizes, int n_in,
                              void* d_out, int out_size, void* d_ws, size_t ws_size,
                              hipStream_t stream)
{
    const int dims[6] = {256, 220, 150, 100, 60, 17};
    const int N = in_sizes[0] / dims[0];      // 10000
    const int E = in_sizes[1] / 2;            // 320000

    const float* x  = (const float*)d_in[0];
    const int* ei   = (const int*)d_in[1];
    const int* srcv = ei;
    const int* dstv = ei + E;
    const float* Wl[5], *bl[5];
    for (int l = 0; l < 5; ++l) {
        Wl[l] = (const float*)d_in[2 + 2 * l];
        bl[l] = (const float*)d_in[3 + 2 * l];
    }
    const float* gl[4], *bel[4];
    for (int l = 0; l < 4; ++l) {
        gl[l]  = (const float*)d_in[12 + 2 * l];
        bel[l] = (const float*)d_in[13 + 2 * l];
    }
    float* out = (float*)d_out;

    // ---- workspace layout ----
    char* w = (char*)d_ws;
    const long NB  = ((long)N * 4 + 255) & ~255L;
    const long NB1 = ((long)(N + 1) * 4 + 255) & ~255L;
    const long EB  = ((long)E * 4 + 255) & ~255L;
    const long FBB = ((long)N * 224 * 2 + 255) & ~255L;
    const long WTB = ((long)224 * 256 * 2 + 255) & ~255L;

    long o = 0;
    float* dinv      = (float*)(w + o);  o += NB;
    float* stats     = (float*)(w + o);  o += 2048 * 4;   // 4 layers x (cs[256]+cq[256])
    float* wbias     = (float*)(w + o);  o += 1024;
    int*   cnt       = (int*)(w + o);    o += NB;
    int*   row_start = (int*)(w + o);    o += NB1;
    int*   cursor    = (int*)(w + o);    o += NB;
    int*   csr_src   = (int*)(w + o);    o += EB;
    ushort_t* Wt     = (ushort_t*)(w + o); o += WTB;
    ushort_t* h2     = (ushort_t*)(w + o); o += FBB;
    ushort_t* tmpb   = (ushort_t*)(w + o); o += FBB;

    const int eBlk = (E + 255) / 256;
    const float invN = 1.0f / (float)N;

    k_init<<<(N + 255) / 256, 256, 0, stream>>>(cnt, stats, wbias, N);
    k_prep0<<<56, 256, 0, stream>>>(Wl[0], Wt);
    k_hist<<<eBlk, 256, 0, stream>>>(dstv, cnt, E);
    k_scan<<<1, 1024, 0, stream>>>(cnt, row_start, cursor, dinv, N);
    k_fill<<<eBlk, 256, 0, stream>>>(srcv, dstv, cursor, csr_src, E);

    for (int l = 0; l < 5; ++l) {
        const int K  = dims[l];
        const int M  = dims[l + 1];
        const int Kp = pad32(K);
        const int Mp = pad16(M);
        const int ts = (l < 4) ? pad32(M) : 32;

        if (l > 0) {
            const int yW = (Mp + 3) / 4;
            k_prep<<<dim3((Kp + 63) / 64, yW + 1), dim3(64, 4), 0, stream>>>(
                Wl[l], gl[l - 1], bel[l - 1],
                stats + (l - 1) * 512, stats + (l - 1) * 512 + 256,
                Wt, wbias, K, M, Kp, Mp, yW, invN);
        }

        dim3 gg((N + 63) / 64, (Mp + 63) / 64);
        if (l == 0) {
            k_gemm_mfma<256, true><<<gg, 256, 0, stream>>>(x, Wt, wbias, dinv, h2, N, Mp);
        } else {
            switch (Kp) {
                case 224: k_gemm_mfma<224, false><<<gg, 256, 0, stream>>>(tmpb, Wt, wbias, dinv, h2, N, Mp); break;
                case 160: k_gemm_mfma<160, false><<<gg, 256, 0, stream>>>(tmpb, Wt, wbias, dinv, h2, N, Mp); break;
                case 128: k_gemm_mfma<128, false><<<gg, 256, 0, stream>>>(tmpb, Wt, wbias, dinv, h2, N, Mp); break;
                case  64: k_gemm_mfma< 64, false><<<gg, 256, 0, stream>>>(tmpb, Wt, wbias, dinv, h2, N, Mp); break;
            }
        }

        if (l < 4) {
            const int Q = ts / 8;
            uint_t shmt = 0;
            while ((1u << shmt) < (uint_t)Q) ++shmt;
            shmt += 32;
            const ull_t magic = ((1ULL << shmt) + Q - 1) / (ull_t)Q;   // 64-bit (pow2 Q!)
            const long total = (long)N * Q;
            k_agg<<<(int)((total + 255) / 256), 256, 0, stream>>>(
                row_start, csr_src, h2, Mp, dinv, bl[l], tmpb, ts, N, M, Q, magic, shmt);
            k_stats<<<(N + 63) / 64, 256, 0, stream>>>(tmpb, ts,
                stats + l * 512, stats + l * 512 + 256, N);
        } else {
            k_agg_final<<<(N + 15) / 16, dim3(16, 16), 0, stream>>>(
                row_start, csr_src, h2, dinv, bl[l], out, N, M);
        }
    }
}